// Round 5
// baseline (845.528 us; speedup 1.0000x reference)
//
#include <hip/hip_runtime.h>
#include <hip/hip_bf16.h>
#include <cstdint>
#include <cstddef>

typedef __attribute__((ext_vector_type(4))) float f32x4;
typedef __attribute__((ext_vector_type(8))) __bf16 bf16x8;

constexpr int Bc = 4, Sc = 2048, Dc = 1024, Hc = 16, HDc = 64;
constexpr int Mrows = Bc * Sc;   // 8192
constexpr int Kdim = Dc;         // 1024
constexpr int Ndim = Dc;         // 1024

__device__ __forceinline__ void gload_lds16(const void* g, void* lds) {
  __builtin_amdgcn_global_load_lds(
      (const __attribute__((address_space(1))) void*)g,
      (__attribute__((address_space(3))) void*)lds, 16, 0, 0);
}

// ---------------- fp32 -> bf16 converts ----------------
__global__ void cvt_f32_to_bf16(const float* __restrict__ src,
                                __bf16* __restrict__ dst, int n4) {
  int i = blockIdx.x * blockDim.x + threadIdx.x;
  if (i >= n4) return;
  float4 f = ((const float4*)src)[i];
  union { __bf16 h[4]; uint2 u; } p;
  p.h[0] = (__bf16)f.x; p.h[1] = (__bf16)f.y;
  p.h[2] = (__bf16)f.z; p.h[3] = (__bf16)f.w;
  ((uint2*)dst)[i] = p.u;
}

__global__ void cvt4_f32_to_bf16(const float* __restrict__ s0, const float* __restrict__ s1,
                                 const float* __restrict__ s2, const float* __restrict__ s3,
                                 __bf16* __restrict__ d0, __bf16* __restrict__ d1,
                                 __bf16* __restrict__ d2, __bf16* __restrict__ d3, int n4each) {
  int i = blockIdx.x * blockDim.x + threadIdx.x;
  int which = i / n4each, j = i - which * n4each;
  const float* s = which == 0 ? s0 : which == 1 ? s1 : which == 2 ? s2 : s3;
  __bf16* d = which == 0 ? d0 : which == 1 ? d1 : which == 2 ? d2 : d3;
  float4 f = ((const float4*)s)[j];
  union { __bf16 h[4]; uint2 u; } p;
  p.h[0] = (__bf16)f.x; p.h[1] = (__bf16)f.y;
  p.h[2] = (__bf16)f.z; p.h[3] = (__bf16)f.w;
  ((uint2*)d)[j] = p.u;
}

// ---------------- GEMM: C[M,N] = A[M,K] * Bw[N,K]^T + bias ----------------
// OUT_MODE 0: bf16 out, per-head layout [B,H,S,HD], (acc+bias)*scale
// OUT_MODE 1: fp32 out, row-major [M,N]
// OUT_MODE 2: bf16 out, transposed per-head layout [B,H,HD,S] (for V^T)
template<int OUT_MODE>
__global__ __launch_bounds__(256, 2)
void gemm_bt(const __bf16* __restrict__ A, const __bf16* __restrict__ Bw,
             const float* __restrict__ bias, void* __restrict__ outp,
             float scale)
{
  __shared__ __align__(16) __bf16 As[128 * 32];
  __shared__ __align__(16) __bf16 Bs[128 * 32];
  const int tid = threadIdx.x;
  const int wave = tid >> 6, lane = tid & 63;
  const int wr = wave >> 1, wc = wave & 1;
  const int r = lane & 15, hi = lane >> 4;
  const int m0 = blockIdx.y * 128, n0 = blockIdx.x * 128;

  f32x4 acc[4][4] = {};

  for (int k0 = 0; k0 < Kdim; k0 += 32) {
    #pragma unroll
    for (int c = 0; c < 2; ++c) {
      int chunk = c * 256 + wave * 64 + lane;
      int row = chunk >> 2;
      int hc = (chunk & 3) ^ (row & 3);   // pre-swizzled source block
      gload_lds16(A  + (size_t)(m0 + row) * Kdim + k0 + hc * 8,
                  &As[(size_t)(c * 256 + wave * 64) * 8]);
      gload_lds16(Bw + (size_t)(n0 + row) * Kdim + k0 + hc * 8,
                  &Bs[(size_t)(c * 256 + wave * 64) * 8]);
    }
    __syncthreads();
    bf16x8 af[4], bfr[4];
    #pragma unroll
    for (int m = 0; m < 4; ++m) {
      int rowl = wr * 64 + m * 16 + r;
      af[m] = *(const bf16x8*)&As[rowl * 32 + ((hi ^ (rowl & 3)) * 8)];
    }
    #pragma unroll
    for (int n = 0; n < 4; ++n) {
      int rowl = wc * 64 + n * 16 + r;
      bfr[n] = *(const bf16x8*)&Bs[rowl * 32 + ((hi ^ (rowl & 3)) * 8)];
    }
    #pragma unroll
    for (int m = 0; m < 4; ++m)
      #pragma unroll
      for (int n = 0; n < 4; ++n)
        acc[m][n] = __builtin_amdgcn_mfma_f32_16x16x32_bf16(af[m], bfr[n], acc[m][n], 0, 0, 0);
    __syncthreads();
  }

  if (OUT_MODE == 2) {
    #pragma unroll
    for (int m = 0; m < 4; ++m)
      #pragma unroll
      for (int n = 0; n < 4; ++n) {
        int row0 = m0 + wr * 64 + m * 16 + hi * 4;
        int col  = n0 + wc * 64 + n * 16 + r;
        int b = row0 >> 11, s = row0 & (Sc - 1);
        int h = col >> 6, d = col & 63;
        union { __bf16 hh[4]; uint2 u; } w;
        #pragma unroll
        for (int rg = 0; rg < 4; ++rg)
          w.hh[rg] = (__bf16)(acc[m][n][rg] + bias[col]);
        *(uint2*)&((__bf16*)outp)[(((size_t)(b * Hc + h) * HDc + d) << 11) + s] = w.u;
      }
  } else {
    #pragma unroll
    for (int m = 0; m < 4; ++m)
      #pragma unroll
      for (int n = 0; n < 4; ++n)
        #pragma unroll
        for (int rg = 0; rg < 4; ++rg) {
          int row_g = m0 + wr * 64 + m * 16 + hi * 4 + rg;
          int col_g = n0 + wc * 64 + n * 16 + r;
          float v = (acc[m][n][rg] + bias[col_g]) * scale;
          if (OUT_MODE == 0) {
            int b = row_g >> 11, s = row_g & (Sc - 1);
            int h = col_g >> 6, d = col_g & 63;
            ((__bf16*)outp)[((((size_t)b * Hc + h) * Sc + s) << 6) + d] = (__bf16)v;
          } else {
            ((float*)outp)[(size_t)row_g * Dc + col_g] = v;
          }
        }
  }
}

// ---------------- causal flash attention, split-KV ----------------
// Qh/Kh: [B*H][S][64] bf16 (Q pre-scaled by log2e/8 -> log2-domain softmax).
// Vt: [B*H][64][S] bf16. out: [B][S][D] bf16.
// One block = one 64-row q-tile; wave0 kv-tiles [0,half), wave1 [half,T); LDS merge.
__global__ __launch_bounds__(128, 4)
void attn_causal(const __bf16* __restrict__ Qh, const __bf16* __restrict__ Kh,
                 const __bf16* __restrict__ Vt, __bf16* __restrict__ outp)
{
  __shared__ __align__(16) float OaS[4][4][64][4];  // 16 KB (wave1 partial O^T)
  __shared__ float MS[4][64];                        // 1 KB
  __shared__ float LS[4][64];                        // 1 KB

  const int tid = threadIdx.x;
  const int wave = tid >> 6, lane = tid & 63;
  const int r = lane & 15, hi = lane >> 4;
  const int bh = blockIdx.y;
  const int qt = 31 - (int)blockIdx.x;              // longest blocks first
  const int q0 = qt * 64;
  const __bf16* Q = Qh + (size_t)bh * (Sc * HDc);
  const __bf16* K = Kh + (size_t)bh * (Sc * HDc);
  const __bf16* V = Vt + (size_t)bh * (HDc * Sc);

  // Q fragments (B-operand: col=r, k=hi*8+j per 32-chunk)
  bf16x8 qf[4][2];
  #pragma unroll
  for (int m = 0; m < 4; ++m)
    #pragma unroll
    for (int kc = 0; kc < 2; ++kc)
      qf[m][kc] = *(const bf16x8*)&Q[(size_t)(q0 + m * 16 + r) * 64 + kc * 32 + hi * 8];

  f32x4 o_acc[4][4] = {};   // O^T: row hd = n*16+hi*4+rg, col q = m*16+r
  float mrow[4], lrow[4];
  #pragma unroll
  for (int m = 0; m < 4; ++m) { mrow[m] = -1e30f; lrow[m] = 0.f; }

  const int T = qt + 1;
  const int half = (T + 1) >> 1;
  const int t0 = wave ? half : 0;
  const int t1 = wave ? T : half;

  bf16x8 kf[4][2], vf[4][2], pb[4][2];

  // preload first tile of this wave's range (in-bounds even if range empty)
  #pragma unroll
  for (int n = 0; n < 4; ++n)
    #pragma unroll
    for (int kc = 0; kc < 2; ++kc) {
      kf[n][kc] = *(const bf16x8*)&K[(size_t)(t0 * 64 + n * 16 + r) * 64 + kc * 32 + hi * 8];
      vf[n][kc] = *(const bf16x8*)&V[(size_t)(n * 16 + r) * Sc + t0 * 64 + kc * 32 + hi * 8];
    }

  for (int t = t0; t < t1; ++t) {
    const bool diag = (t == T - 1);
    const int kvn = (t + 1) * 64;

    // ---- phase 1: QK^T (swapped) + log2-softmax + in-register P exchange ----
    #pragma unroll
    for (int m = 0; m < 4; ++m) {
      f32x4 sn[4];
      __builtin_amdgcn_s_setprio(1);
      #pragma unroll
      for (int n = 0; n < 4; ++n) {
        f32x4 z = {0.f, 0.f, 0.f, 0.f};
        sn[n] = __builtin_amdgcn_mfma_f32_16x16x32_bf16(kf[n][0], qf[m][0], z, 0, 0, 0);
        sn[n] = __builtin_amdgcn_mfma_f32_16x16x32_bf16(kf[n][1], qf[m][1], sn[n], 0, 0, 0);
      }
      __builtin_amdgcn_s_setprio(0);
      if (diag) {
        #pragma unroll
        for (int n = 0; n < 4; ++n)
          #pragma unroll
          for (int rg = 0; rg < 4; ++rg)
            if (n * 16 + hi * 4 + rg > m * 16 + r) sn[n][rg] = -1e30f;
      }
      float mx = fmaxf(fmaxf(fmaxf(sn[0][0], sn[0][1]), fmaxf(sn[0][2], sn[0][3])),
                       fmaxf(fmaxf(sn[1][0], sn[1][1]), fmaxf(sn[1][2], sn[1][3])));
      mx = fmaxf(mx, fmaxf(fmaxf(fmaxf(sn[2][0], sn[2][1]), fmaxf(sn[2][2], sn[2][3])),
                           fmaxf(fmaxf(sn[3][0], sn[3][1]), fmaxf(sn[3][2], sn[3][3]))));
      mx = fmaxf(mx, __shfl_xor(mx, 16));
      mx = fmaxf(mx, __shfl_xor(mx, 32));
      float mloc = mrow[m];
      if (__any(mx > mloc + 8.f)) {          // T13 defer-max (log2 domain)
        float mnew = fmaxf(mloc, mx);
        float sc = __builtin_exp2f(mloc - mnew);
        lrow[m] *= sc;
        #pragma unroll
        for (int n = 0; n < 4; ++n) o_acc[m][n] *= sc;
        mrow[m] = mnew; mloc = mnew;
      }
      float rs = 0.f;
      #pragma unroll
      for (int n = 0; n < 4; ++n)
        #pragma unroll
        for (int rg = 0; rg < 4; ++rg) {
          float p = __builtin_exp2f(sn[n][rg] - mloc);
          sn[n][rg] = p;
          rs += p;
        }
      rs += __shfl_xor(rs, 16);
      rs += __shfl_xor(rs, 32);
      lrow[m] += rs;

      // exchange P^T -> B-operand layout (R3-proven: perm32 + xor16 + select).
      // After perm32: p0a@(r,hi)=P_{2kc+(hi>>1)} from hi'=(hi&1); p1a: hi'=2+(hi&1).
      // Target: u[0]/u[1] need hi'=2(hi&1); u[2]/u[3] need hi'=2(hi&1)+1.
      #pragma unroll
      for (int kc = 0; kc < 2; ++kc) {
        uint32_t p0a, p0b, p1a, p1b;
        asm("v_cvt_pk_bf16_f32 %0, %1, %2" : "=v"(p0a) : "v"(sn[2*kc][0]),   "v"(sn[2*kc][1]));
        asm("v_cvt_pk_bf16_f32 %0, %1, %2" : "=v"(p0b) : "v"(sn[2*kc][2]),   "v"(sn[2*kc][3]));
        asm("v_cvt_pk_bf16_f32 %0, %1, %2" : "=v"(p1a) : "v"(sn[2*kc+1][0]), "v"(sn[2*kc+1][1]));
        asm("v_cvt_pk_bf16_f32 %0, %1, %2" : "=v"(p1b) : "v"(sn[2*kc+1][2]), "v"(sn[2*kc+1][3]));
        asm("v_permlane32_swap_b32 %0, %1" : "+v"(p0a), "+v"(p1a));
        asm("v_permlane32_swap_b32 %0, %1" : "+v"(p0b), "+v"(p1b));
        uint32_t Xa = (uint32_t)__shfl_xor((int)p1a, 16);
        uint32_t Xb = (uint32_t)__shfl_xor((int)p1b, 16);
        uint32_t Ya = (uint32_t)__shfl_xor((int)p0a, 16);
        uint32_t Yb = (uint32_t)__shfl_xor((int)p0b, 16);
        union { uint32_t u[4]; bf16x8 v; } pk;
        pk.u[0] = (hi & 1) ? Xa : p0a;
        pk.u[1] = (hi & 1) ? Xb : p0b;
        pk.u[2] = (hi & 1) ? p1a : Ya;
        pk.u[3] = (hi & 1) ? p1b : Yb;
        pb[m][kc] = pk.v;
      }
    }

    // prefetch next K tile (kf dead after phase 1)
    if (t + 1 < t1) {
      #pragma unroll
      for (int n = 0; n < 4; ++n)
        #pragma unroll
        for (int kc = 0; kc < 2; ++kc)
          kf[n][kc] = *(const bf16x8*)&K[(size_t)(kvn + n * 16 + r) * 64 + kc * 32 + hi * 8];
    }

    // ---- phase 2: PV (swapped: O^T += V^T-frag * P-frag) ----
    __builtin_amdgcn_s_setprio(1);
    #pragma unroll
    for (int m = 0; m < 4; ++m)
      #pragma unroll
      for (int n = 0; n < 4; ++n) {
        o_acc[m][n] = __builtin_amdgcn_mfma_f32_16x16x32_bf16(vf[n][0], pb[m][0], o_acc[m][n], 0, 0, 0);
        o_acc[m][n] = __builtin_amdgcn_mfma_f32_16x16x32_bf16(vf[n][1], pb[m][1], o_acc[m][n], 0, 0, 0);
      }
    __builtin_amdgcn_s_setprio(0);

    // prefetch next V tile (vf dead after phase 2)
    if (t + 1 < t1) {
      #pragma unroll
      for (int n = 0; n < 4; ++n)
        #pragma unroll
        for (int kc = 0; kc < 2; ++kc)
          vf[n][kc] = *(const bf16x8*)&V[(size_t)(n * 16 + r) * Sc + kvn + kc * 32 + hi * 8];
    }
  }

  // ---- merge wave1 partial into wave0, then epilogue ----
  if (wave == 1) {
    #pragma unroll
    for (int m = 0; m < 4; ++m) {
      MS[m][lane] = mrow[m];
      LS[m][lane] = lrow[m];
      #pragma unroll
      for (int n = 0; n < 4; ++n)
        *(f32x4*)OaS[m][n][lane] = o_acc[m][n];
    }
  }
  __syncthreads();
  if (wave == 0) {
    const int b = bh >> 4, h = bh & 15;
    #pragma unroll
    for (int m = 0; m < 4; ++m) {
      float mB = MS[m][lane], lB = LS[m][lane];
      float mF = fmaxf(mrow[m], mB);
      float aA = __builtin_exp2f(mrow[m] - mF);
      float aB = __builtin_exp2f(mB - mF);
      float inv = 1.f / (lrow[m] * aA + lB * aB);
      size_t row = (size_t)b * Sc + q0 + m * 16 + r;
      #pragma unroll
      for (int n = 0; n < 4; ++n) {
        f32x4 oB = *(f32x4*)OaS[m][n][lane];
        union { __bf16 hh[4]; uint2 u; } w;
        #pragma unroll
        for (int rg = 0; rg < 4; ++rg)
          w.hh[rg] = (__bf16)((o_acc[m][n][rg] * aA + oB[rg] * aB) * inv);
        int col = h * 64 + n * 16 + hi * 4;
        *(uint2*)&outp[row * Dc + col] = w.u;
      }
    }
  }
}

// ---------------- launch ----------------
extern "C" void kernel_launch(void* const* d_in, const int* in_sizes, int n_in,
                              void* d_out, int out_size, void* d_ws, size_t ws_size,
                              hipStream_t stream) {
  const float* q  = (const float*)d_in[0];
  const float* k  = (const float*)d_in[1];
  const float* v  = (const float*)d_in[2];
  const float* Wq = (const float*)d_in[4];
  const float* bq = (const float*)d_in[5];
  const float* Wk = (const float*)d_in[6];
  const float* bk = (const float*)d_in[7];
  const float* Wv = (const float*)d_in[8];
  const float* bv = (const float*)d_in[9];
  const float* Wo = (const float*)d_in[10];
  const float* bo = (const float*)d_in[11];

  char* ws = (char*)d_ws;
  constexpr size_t MB = 1u << 20;
  __bf16* Wqb = (__bf16*)(ws + 0 * MB);
  __bf16* Wkb = (__bf16*)(ws + 2 * MB);
  __bf16* Wvb = (__bf16*)(ws + 4 * MB);
  __bf16* Wob = (__bf16*)(ws + 6 * MB);
  __bf16* Xbf = (__bf16*)(ws + 8 * MB);    // 16 MB: X (reused), then attn out
  __bf16* QhB = (__bf16*)(ws + 24 * MB);
  __bf16* KhB = (__bf16*)(ws + 40 * MB);
  __bf16* VtB = (__bf16*)(ws + 56 * MB);   // V^T: [B*H][64][S]

  const int nW4 = (Dc * Dc) / 4;           // 262144
  const int nX4 = (Mrows * Dc) / 4;        // 2097152
  cvt4_f32_to_bf16<<<(4 * nW4) / 256, 256, 0, stream>>>(Wq, Wk, Wv, Wo, Wqb, Wkb, Wvb, Wob, nW4);

  const float qscale = 0.125f * 1.44269504f;  // fold 1/sqrt(64) and log2(e)
  dim3 gg(Ndim / 128, Mrows / 128);  // (8, 64)
  cvt_f32_to_bf16<<<(nX4 + 255) / 256, 256, 0, stream>>>(q, Xbf, nX4);
  gemm_bt<0><<<gg, 256, 0, stream>>>(Xbf, Wqb, bq, QhB, qscale);
  cvt_f32_to_bf16<<<(nX4 + 255) / 256, 256, 0, stream>>>(k, Xbf, nX4);
  gemm_bt<0><<<gg, 256, 0, stream>>>(Xbf, Wkb, bk, KhB, 1.0f);
  cvt_f32_to_bf16<<<(nX4 + 255) / 256, 256, 0, stream>>>(v, Xbf, nX4);
  gemm_bt<2><<<gg, 256, 0, stream>>>(Xbf, Wvb, bv, VtB, 1.0f);

  attn_causal<<<dim3(32, Bc * Hc), 128, 0, stream>>>(QhB, KhB, VtB, Xbf);

  gemm_bt<1><<<gg, 256, 0, stream>>>(Xbf, Wob, bo, d_out, 1.0f);
}

// Round 6
// 318.782 us; speedup vs baseline: 2.6524x; 2.6524x over previous
//
#include <hip/hip_runtime.h>
#include <hip/hip_bf16.h>
#include <cstdint>
#include <cstddef>

typedef __attribute__((ext_vector_type(4))) float f32x4;
typedef __attribute__((ext_vector_type(8))) __bf16 bf16x8;

constexpr int Bc = 4, Sc = 2048, Dc = 1024, Hc = 16, HDc = 64;
constexpr int Mrows = Bc * Sc;   // 8192
constexpr int Kdim = Dc;         // 1024

__device__ __forceinline__ void gload_lds16(const void* g, void* lds) {
  __builtin_amdgcn_global_load_lds(
      (const __attribute__((address_space(1))) void*)g,
      (__attribute__((address_space(3))) void*)lds, 16, 0, 0);
}

// ---------------- fp32 -> bf16 weight converts (one fused launch) ----------------
__global__ void cvt4_f32_to_bf16(const float* __restrict__ s0, const float* __restrict__ s1,
                                 const float* __restrict__ s2, const float* __restrict__ s3,
                                 __bf16* __restrict__ d0, __bf16* __restrict__ d1,
                                 __bf16* __restrict__ d2, __bf16* __restrict__ d3, int n4each) {
  int i = blockIdx.x * blockDim.x + threadIdx.x;
  int which = i / n4each, j = i - which * n4each;
  const float* s = which == 0 ? s0 : which == 1 ? s1 : which == 2 ? s2 : s3;
  __bf16* d = which == 0 ? d0 : which == 1 ? d1 : which == 2 ? d2 : d3;
  float4 f = ((const float4*)s)[j];
  union { __bf16 h[4]; uint2 u; } p;
  p.h[0] = (__bf16)f.x; p.h[1] = (__bf16)f.y;
  p.h[2] = (__bf16)f.z; p.h[3] = (__bf16)f.w;
  ((uint2*)d)[j] = p.u;
}

// ---------------- fused QKV GEMM ----------------
// A (fp32, per-projection input) staged via registers->LDS with on-the-fly bf16 cvt;
// B = Wcat bf16 [3072][1024] (Wq|Wk|Wv rows) via global_load_lds.
// Epilogue block-uniform per projection:
//   proj 0 -> Qh [B,H,S,64] *qscale; proj 1 -> Kh [B,H,S,64]; proj 2 -> Vt [B,H,64,S].
__global__ __launch_bounds__(256, 2)
void gemm_qkv(const float* __restrict__ qin, const float* __restrict__ kin,
              const float* __restrict__ vin, const __bf16* __restrict__ Wcat,
              const float* __restrict__ bq, const float* __restrict__ bk,
              const float* __restrict__ bv,
              __bf16* __restrict__ Qh, __bf16* __restrict__ Kh,
              __bf16* __restrict__ Vt, float qscale)
{
  __shared__ __align__(16) __bf16 As[128 * 32];
  __shared__ __align__(16) __bf16 Bs[128 * 32];
  const int tid = threadIdx.x;
  const int wave = tid >> 6, lane = tid & 63;
  const int wr = wave >> 1, wc = wave & 1;
  const int r = lane & 15, hi = lane >> 4;
  const int m0 = blockIdx.y * 128, n0 = blockIdx.x * 128;
  const int proj = n0 >> 10;                       // block-uniform: 0=Q 1=K 2=V
  const float* Xa = proj == 0 ? qin : proj == 1 ? kin : vin;

  f32x4 acc[4][4] = {};

  for (int k0 = 0; k0 < Kdim; k0 += 32) {
    // A: fp32 -> bf16 register staging, same swizzled chunk layout as gload path
    #pragma unroll
    for (int c = 0; c < 2; ++c) {
      int chunk = c * 256 + tid;
      int row = chunk >> 2;
      int cw = chunk & 3;
      int hc = cw ^ (row & 3);
      const float* src = Xa + (size_t)(m0 + row) * Kdim + k0 + hc * 8;
      float4 f0 = *(const float4*)src;
      float4 f1 = *(const float4*)(src + 4);
      union { __bf16 h[8]; uint4 u; } pk;
      pk.h[0] = (__bf16)f0.x; pk.h[1] = (__bf16)f0.y;
      pk.h[2] = (__bf16)f0.z; pk.h[3] = (__bf16)f0.w;
      pk.h[4] = (__bf16)f1.x; pk.h[5] = (__bf16)f1.y;
      pk.h[6] = (__bf16)f1.z; pk.h[7] = (__bf16)f1.w;
      *(uint4*)&As[(size_t)chunk * 8] = pk.u;
    }
    // B: async global->LDS, pre-swizzled source
    #pragma unroll
    for (int c = 0; c < 2; ++c) {
      int chunk = c * 256 + wave * 64 + lane;
      int row = chunk >> 2;
      int hc = (chunk & 3) ^ (row & 3);
      gload_lds16(Wcat + (size_t)(n0 + row) * Kdim + k0 + hc * 8,
                  &Bs[(size_t)(c * 256 + wave * 64) * 8]);
    }
    __syncthreads();
    bf16x8 af[4], bfr[4];
    #pragma unroll
    for (int m = 0; m < 4; ++m) {
      int rowl = wr * 64 + m * 16 + r;
      af[m] = *(const bf16x8*)&As[rowl * 32 + ((hi ^ (rowl & 3)) * 8)];
    }
    #pragma unroll
    for (int n = 0; n < 4; ++n) {
      int rowl = wc * 64 + n * 16 + r;
      bfr[n] = *(const bf16x8*)&Bs[rowl * 32 + ((hi ^ (rowl & 3)) * 8)];
    }
    #pragma unroll
    for (int m = 0; m < 4; ++m)
      #pragma unroll
      for (int n = 0; n < 4; ++n)
        acc[m][n] = __builtin_amdgcn_mfma_f32_16x16x32_bf16(af[m], bfr[n], acc[m][n], 0, 0, 0);
    __syncthreads();
  }

  const float* bias = proj == 0 ? bq : proj == 1 ? bk : bv;
  if (proj < 2) {
    __bf16* out = proj == 0 ? Qh : Kh;
    const float sc = proj == 0 ? qscale : 1.0f;
    #pragma unroll
    for (int m = 0; m < 4; ++m)
      #pragma unroll
      for (int n = 0; n < 4; ++n)
        #pragma unroll
        for (int rg = 0; rg < 4; ++rg) {
          int row_g = m0 + wr * 64 + m * 16 + hi * 4 + rg;
          int col_g = n0 + wc * 64 + n * 16 + r;
          int c = col_g & 1023, h = c >> 6, d = c & 63;
          int b = row_g >> 11, s = row_g & (Sc - 1);
          float v = (acc[m][n][rg] + bias[c]) * sc;
          out[((((size_t)b * Hc + h) * Sc + s) << 6) + d] = (__bf16)v;
        }
  } else {
    #pragma unroll
    for (int m = 0; m < 4; ++m)
      #pragma unroll
      for (int n = 0; n < 4; ++n) {
        int row0 = m0 + wr * 64 + m * 16 + hi * 4;
        int col_g = n0 + wc * 64 + n * 16 + r;
        int c = col_g & 1023, h = c >> 6, d = c & 63;
        int b = row0 >> 11, s = row0 & (Sc - 1);
        union { __bf16 hh[4]; uint2 u; } w;
        #pragma unroll
        for (int rg = 0; rg < 4; ++rg)
          w.hh[rg] = (__bf16)(acc[m][n][rg] + bias[c]);
        *(uint2*)&Vt[((((size_t)b * Hc + h) * HDc + d) << 11) + s] = w.u;
      }
  }
}

// ---------------- out-projection GEMM: fp32 out = A[M,K](bf16) * Wo^T + bo ----------------
__global__ __launch_bounds__(256, 2)
void gemm_out(const __bf16* __restrict__ A, const __bf16* __restrict__ Bw,
              const float* __restrict__ bias, float* __restrict__ outp)
{
  __shared__ __align__(16) __bf16 As[128 * 32];
  __shared__ __align__(16) __bf16 Bs[128 * 32];
  const int tid = threadIdx.x;
  const int wave = tid >> 6, lane = tid & 63;
  const int wr = wave >> 1, wc = wave & 1;
  const int r = lane & 15, hi = lane >> 4;
  const int m0 = blockIdx.y * 128, n0 = blockIdx.x * 128;

  f32x4 acc[4][4] = {};

  for (int k0 = 0; k0 < Kdim; k0 += 32) {
    #pragma unroll
    for (int c = 0; c < 2; ++c) {
      int chunk = c * 256 + wave * 64 + lane;
      int row = chunk >> 2;
      int hc = (chunk & 3) ^ (row & 3);
      gload_lds16(A  + (size_t)(m0 + row) * Kdim + k0 + hc * 8,
                  &As[(size_t)(c * 256 + wave * 64) * 8]);
      gload_lds16(Bw + (size_t)(n0 + row) * Kdim + k0 + hc * 8,
                  &Bs[(size_t)(c * 256 + wave * 64) * 8]);
    }
    __syncthreads();
    bf16x8 af[4], bfr[4];
    #pragma unroll
    for (int m = 0; m < 4; ++m) {
      int rowl = wr * 64 + m * 16 + r;
      af[m] = *(const bf16x8*)&As[rowl * 32 + ((hi ^ (rowl & 3)) * 8)];
    }
    #pragma unroll
    for (int n = 0; n < 4; ++n) {
      int rowl = wc * 64 + n * 16 + r;
      bfr[n] = *(const bf16x8*)&Bs[rowl * 32 + ((hi ^ (rowl & 3)) * 8)];
    }
    #pragma unroll
    for (int m = 0; m < 4; ++m)
      #pragma unroll
      for (int n = 0; n < 4; ++n)
        acc[m][n] = __builtin_amdgcn_mfma_f32_16x16x32_bf16(af[m], bfr[n], acc[m][n], 0, 0, 0);
    __syncthreads();
  }

  #pragma unroll
  for (int m = 0; m < 4; ++m)
    #pragma unroll
    for (int n = 0; n < 4; ++n)
      #pragma unroll
      for (int rg = 0; rg < 4; ++rg) {
        int row_g = m0 + wr * 64 + m * 16 + hi * 4 + rg;
        int col_g = n0 + wc * 64 + n * 16 + r;
        outp[(size_t)row_g * Dc + col_g] = acc[m][n][rg] + bias[col_g];
      }
}

// ---------------- causal flash attention, split-KV ----------------
// Qh/Kh: [B*H][S][64] bf16 (Q pre-scaled by log2e/8 -> log2-domain softmax).
// Vt: [B*H][64][S] bf16. out: [B][S][D] bf16.
// One block = one 64-row q-tile; wave0 kv-tiles [0,half), wave1 [half,T); LDS merge.
__global__ __launch_bounds__(128, 2)
void attn_causal(const __bf16* __restrict__ Qh, const __bf16* __restrict__ Kh,
                 const __bf16* __restrict__ Vt, __bf16* __restrict__ outp)
{
  __shared__ __align__(16) float OaS[4][4][64][4];  // 16 KB (wave1 partial O^T)
  __shared__ float MS[4][64];                        // 1 KB
  __shared__ float LS[4][64];                        // 1 KB

  const int tid = threadIdx.x;
  const int wave = tid >> 6, lane = tid & 63;
  const int r = lane & 15, hi = lane >> 4;
  const int bh = blockIdx.y;
  const int qt = 31 - (int)blockIdx.x;              // longest blocks first
  const int q0 = qt * 64;
  const __bf16* Q = Qh + (size_t)bh * (Sc * HDc);
  const __bf16* K = Kh + (size_t)bh * (Sc * HDc);
  const __bf16* V = Vt + (size_t)bh * (HDc * Sc);

  // Q fragments (B-operand: col=r, k=hi*8+j per 32-chunk)
  bf16x8 qf[4][2];
  #pragma unroll
  for (int m = 0; m < 4; ++m)
    #pragma unroll
    for (int kc = 0; kc < 2; ++kc)
      qf[m][kc] = *(const bf16x8*)&Q[(size_t)(q0 + m * 16 + r) * 64 + kc * 32 + hi * 8];

  f32x4 o_acc[4][4] = {};   // O^T: row hd = n*16+hi*4+rg, col q = m*16+r
  float mrow[4], lrow[4];
  #pragma unroll
  for (int m = 0; m < 4; ++m) { mrow[m] = -1e30f; lrow[m] = 0.f; }

  const int T = qt + 1;
  const int half = (T + 1) >> 1;
  const int t0 = wave ? half : 0;
  const int t1 = wave ? T : half;

  bf16x8 kf[4][2], vf[4][2], pb[4][2];

  // preload first tile of this wave's range (in-bounds even if range empty)
  #pragma unroll
  for (int n = 0; n < 4; ++n)
    #pragma unroll
    for (int kc = 0; kc < 2; ++kc) {
      kf[n][kc] = *(const bf16x8*)&K[(size_t)(t0 * 64 + n * 16 + r) * 64 + kc * 32 + hi * 8];
      vf[n][kc] = *(const bf16x8*)&V[(size_t)(n * 16 + r) * Sc + t0 * 64 + kc * 32 + hi * 8];
    }

  for (int t = t0; t < t1; ++t) {
    const bool diag = (t == T - 1);
    const int kvn = (t + 1) * 64;

    // ---- phase 1: QK^T (swapped) + log2-softmax + in-register P exchange ----
    #pragma unroll
    for (int m = 0; m < 4; ++m) {
      f32x4 sn[4];
      __builtin_amdgcn_s_setprio(1);
      #pragma unroll
      for (int n = 0; n < 4; ++n) {
        f32x4 z = {0.f, 0.f, 0.f, 0.f};
        sn[n] = __builtin_amdgcn_mfma_f32_16x16x32_bf16(kf[n][0], qf[m][0], z, 0, 0, 0);
        sn[n] = __builtin_amdgcn_mfma_f32_16x16x32_bf16(kf[n][1], qf[m][1], sn[n], 0, 0, 0);
      }
      __builtin_amdgcn_s_setprio(0);
      if (diag) {
        #pragma unroll
        for (int n = 0; n < 4; ++n)
          #pragma unroll
          for (int rg = 0; rg < 4; ++rg)
            if (n * 16 + hi * 4 + rg > m * 16 + r) sn[n][rg] = -1e30f;
      }
      float mx = fmaxf(fmaxf(fmaxf(sn[0][0], sn[0][1]), fmaxf(sn[0][2], sn[0][3])),
                       fmaxf(fmaxf(sn[1][0], sn[1][1]), fmaxf(sn[1][2], sn[1][3])));
      mx = fmaxf(mx, fmaxf(fmaxf(fmaxf(sn[2][0], sn[2][1]), fmaxf(sn[2][2], sn[2][3])),
                           fmaxf(fmaxf(sn[3][0], sn[3][1]), fmaxf(sn[3][2], sn[3][3]))));
      mx = fmaxf(mx, __shfl_xor(mx, 16));
      mx = fmaxf(mx, __shfl_xor(mx, 32));
      float mloc = mrow[m];
      if (__any(mx > mloc + 8.f)) {          // T13 defer-max (log2 domain)
        float mnew = fmaxf(mloc, mx);
        float sc = __builtin_exp2f(mloc - mnew);
        lrow[m] *= sc;
        #pragma unroll
        for (int n = 0; n < 4; ++n) o_acc[m][n] *= sc;
        mrow[m] = mnew; mloc = mnew;
      }
      float rs = 0.f;
      #pragma unroll
      for (int n = 0; n < 4; ++n)
        #pragma unroll
        for (int rg = 0; rg < 4; ++rg) {
          float p = __builtin_exp2f(sn[n][rg] - mloc);
          sn[n][rg] = p;
          rs += p;
        }
      rs += __shfl_xor(rs, 16);
      rs += __shfl_xor(rs, 32);
      lrow[m] += rs;

      // exchange P^T -> B-operand layout (R3-proven: perm32 + xor16 + select).
      #pragma unroll
      for (int kc = 0; kc < 2; ++kc) {
        uint32_t p0a, p0b, p1a, p1b;
        asm("v_cvt_pk_bf16_f32 %0, %1, %2" : "=v"(p0a) : "v"(sn[2*kc][0]),   "v"(sn[2*kc][1]));
        asm("v_cvt_pk_bf16_f32 %0, %1, %2" : "=v"(p0b) : "v"(sn[2*kc][2]),   "v"(sn[2*kc][3]));
        asm("v_cvt_pk_bf16_f32 %0, %1, %2" : "=v"(p1a) : "v"(sn[2*kc+1][0]), "v"(sn[2*kc+1][1]));
        asm("v_cvt_pk_bf16_f32 %0, %1, %2" : "=v"(p1b) : "v"(sn[2*kc+1][2]), "v"(sn[2*kc+1][3]));
        asm("v_permlane32_swap_b32 %0, %1" : "+v"(p0a), "+v"(p1a));
        asm("v_permlane32_swap_b32 %0, %1" : "+v"(p0b), "+v"(p1b));
        uint32_t Xa = (uint32_t)__shfl_xor((int)p1a, 16);
        uint32_t Xb = (uint32_t)__shfl_xor((int)p1b, 16);
        uint32_t Ya = (uint32_t)__shfl_xor((int)p0a, 16);
        uint32_t Yb = (uint32_t)__shfl_xor((int)p0b, 16);
        union { uint32_t u[4]; bf16x8 v; } pk;
        pk.u[0] = (hi & 1) ? Xa : p0a;
        pk.u[1] = (hi & 1) ? Xb : p0b;
        pk.u[2] = (hi & 1) ? p1a : Ya;
        pk.u[3] = (hi & 1) ? p1b : Yb;
        pb[m][kc] = pk.v;
      }
    }

    // prefetch next K tile (kf dead after phase 1)
    if (t + 1 < t1) {
      #pragma unroll
      for (int n = 0; n < 4; ++n)
        #pragma unroll
        for (int kc = 0; kc < 2; ++kc)
          kf[n][kc] = *(const bf16x8*)&K[(size_t)(kvn + n * 16 + r) * 64 + kc * 32 + hi * 8];
    }

    // ---- phase 2: PV (swapped: O^T += V^T-frag * P-frag) ----
    __builtin_amdgcn_s_setprio(1);
    #pragma unroll
    for (int m = 0; m < 4; ++m)
      #pragma unroll
      for (int n = 0; n < 4; ++n) {
        o_acc[m][n] = __builtin_amdgcn_mfma_f32_16x16x32_bf16(vf[n][0], pb[m][0], o_acc[m][n], 0, 0, 0);
        o_acc[m][n] = __builtin_amdgcn_mfma_f32_16x16x32_bf16(vf[n][1], pb[m][1], o_acc[m][n], 0, 0, 0);
      }
    __builtin_amdgcn_s_setprio(0);

    // prefetch next V tile (vf dead after phase 2)
    if (t + 1 < t1) {
      #pragma unroll
      for (int n = 0; n < 4; ++n)
        #pragma unroll
        for (int kc = 0; kc < 2; ++kc)
          vf[n][kc] = *(const bf16x8*)&V[(size_t)(n * 16 + r) * Sc + kvn + kc * 32 + hi * 8];
    }
  }

  // ---- merge wave1 partial into wave0, then epilogue ----
  if (wave == 1) {
    #pragma unroll
    for (int m = 0; m < 4; ++m) {
      MS[m][lane] = mrow[m];
      LS[m][lane] = lrow[m];
      #pragma unroll
      for (int n = 0; n < 4; ++n)
        *(f32x4*)OaS[m][n][lane] = o_acc[m][n];
    }
  }
  __syncthreads();
  if (wave == 0) {
    const int b = bh >> 4, h = bh & 15;
    #pragma unroll
    for (int m = 0; m < 4; ++m) {
      float mB = MS[m][lane], lB = LS[m][lane];
      float mF = fmaxf(mrow[m], mB);
      float aA = __builtin_exp2f(mrow[m] - mF);
      float aB = __builtin_exp2f(mB - mF);
      float inv = 1.f / (lrow[m] * aA + lB * aB);
      size_t row = (size_t)b * Sc + q0 + m * 16 + r;
      #pragma unroll
      for (int n = 0; n < 4; ++n) {
        f32x4 oB = *(f32x4*)OaS[m][n][lane];
        union { __bf16 hh[4]; uint2 u; } w;
        #pragma unroll
        for (int rg = 0; rg < 4; ++rg)
          w.hh[rg] = (__bf16)((o_acc[m][n][rg] * aA + oB[rg] * aB) * inv);
        int col = h * 64 + n * 16 + hi * 4;
        *(uint2*)&outp[row * Dc + col] = w.u;
      }
    }
  }
}

// ---------------- launch ----------------
extern "C" void kernel_launch(void* const* d_in, const int* in_sizes, int n_in,
                              void* d_out, int out_size, void* d_ws, size_t ws_size,
                              hipStream_t stream) {
  const float* q  = (const float*)d_in[0];
  const float* k  = (const float*)d_in[1];
  const float* v  = (const float*)d_in[2];
  const float* Wq = (const float*)d_in[4];
  const float* bq = (const float*)d_in[5];
  const float* Wk = (const float*)d_in[6];
  const float* bk = (const float*)d_in[7];
  const float* Wv = (const float*)d_in[8];
  const float* bv = (const float*)d_in[9];
  const float* Wo = (const float*)d_in[10];
  const float* bo = (const float*)d_in[11];

  char* ws = (char*)d_ws;
  constexpr size_t MB = 1u << 20;
  __bf16* Wcat = (__bf16*)(ws + 0 * MB);   // Wq|Wk|Wv rows, 6 MB
  __bf16* Wkb  = (__bf16*)(ws + 2 * MB);
  __bf16* Wvb  = (__bf16*)(ws + 4 * MB);
  __bf16* Wob  = (__bf16*)(ws + 6 * MB);
  __bf16* Xbf  = (__bf16*)(ws + 8 * MB);   // attn out, 16 MB
  __bf16* QhB  = (__bf16*)(ws + 24 * MB);
  __bf16* KhB  = (__bf16*)(ws + 40 * MB);
  __bf16* VtB  = (__bf16*)(ws + 56 * MB);  // V^T: [B*H][64][S]

  const int nW4 = (Dc * Dc) / 4;           // 262144
  cvt4_f32_to_bf16<<<(4 * nW4) / 256, 256, 0, stream>>>(Wq, Wk, Wv, Wo, Wcat, Wkb, Wvb, Wob, nW4);

  const float qscale = 0.125f * 1.44269504f;  // fold 1/sqrt(64) and log2(e)
  gemm_qkv<<<dim3(24, Mrows / 128), 256, 0, stream>>>(q, k, v, Wcat, bq, bk, bv,
                                                      QhB, KhB, VtB, qscale);

  attn_causal<<<dim3(32, Bc * Hc), 128, 0, stream>>>(QhB, KhB, VtB, Xbf);

  gemm_out<<<dim3(8, Mrows / 128), 256, 0, stream>>>(Xbf, Wob, bo, (float*)d_out);
}

// Round 10
// 279.274 us; speedup vs baseline: 3.0276x; 1.1415x over previous
//
#include <hip/hip_runtime.h>
#include <hip/hip_bf16.h>
#include <cstdint>
#include <cstddef>

typedef __attribute__((ext_vector_type(4))) float f32x4;
typedef __attribute__((ext_vector_type(8))) __bf16 bf16x8;

constexpr int Bc = 4, Sc = 2048, Dc = 1024, Hc = 16, HDc = 64;
constexpr int Mrows = Bc * Sc;   // 8192
constexpr int Kdim = Dc;         // 1024

__device__ __forceinline__ void gload_lds16(const void* g, void* lds) {
  __builtin_amdgcn_global_load_lds(
      (const __attribute__((address_space(1))) void*)g,
      (__attribute__((address_space(3))) void*)lds, 16, 0, 0);
}

// ---------------- fp32 -> bf16 weight converts (one fused launch) ----------------
__global__ void cvt4_f32_to_bf16(const float* __restrict__ s0, const float* __restrict__ s1,
                                 const float* __restrict__ s2, const float* __restrict__ s3,
                                 __bf16* __restrict__ d0, __bf16* __restrict__ d1,
                                 __bf16* __restrict__ d2, __bf16* __restrict__ d3, int n4each) {
  int i = blockIdx.x * blockDim.x + threadIdx.x;
  int which = i / n4each, j = i - which * n4each;
  const float* s = which == 0 ? s0 : which == 1 ? s1 : which == 2 ? s2 : s3;
  __bf16* d = which == 0 ? d0 : which == 1 ? d1 : which == 2 ? d2 : d3;
  float4 f = ((const float4*)s)[j];
  union { __bf16 h[4]; uint2 u; } p;
  p.h[0] = (__bf16)f.x; p.h[1] = (__bf16)f.y;
  p.h[2] = (__bf16)f.z; p.h[3] = (__bf16)f.w;
  ((uint2*)d)[j] = p.u;
}

// ---------------- fused QKV GEMM ----------------
// XCD swizzle: co-locate all 24 n-blocks of one M-panel on one XCD (A reuse).
__global__ __launch_bounds__(256, 2)
void gemm_qkv(const float* __restrict__ qin, const float* __restrict__ kin,
              const float* __restrict__ vin, const __bf16* __restrict__ Wcat,
              const float* __restrict__ bq, const float* __restrict__ bk,
              const float* __restrict__ bv,
              __bf16* __restrict__ Qh, __bf16* __restrict__ Kh,
              __bf16* __restrict__ Vt, float qscale)
{
  __shared__ __align__(16) __bf16 As[128 * 32];
  __shared__ __align__(16) __bf16 Bs[128 * 32];
  const int tid = threadIdx.x;
  const int wave = tid >> 6, lane = tid & 63;
  const int wr = wave >> 1, wc = wave & 1;
  const int r = lane & 15, hi = lane >> 4;
  // bijective remap: lin -> (xcd = lin&7, s = lin>>3); 8 M-panels per XCD.
  const int lin = (int)blockIdx.y * 24 + (int)blockIdx.x;   // 0..1535
  const int xcd = lin & 7, s8 = lin >> 3;                   // s8: 0..191
  const int my = (xcd << 3) | (s8 / 24);                    // 0..63
  const int mx = s8 % 24;                                   // 0..23
  const int m0 = my * 128, n0 = mx * 128;
  const int proj = n0 >> 10;                       // block-uniform: 0=Q 1=K 2=V
  const float* Xa = proj == 0 ? qin : proj == 1 ? kin : vin;

  f32x4 acc[4][4] = {};

  for (int k0 = 0; k0 < Kdim; k0 += 32) {
    #pragma unroll
    for (int c = 0; c < 2; ++c) {
      int chunk = c * 256 + tid;
      int row = chunk >> 2;
      int cw = chunk & 3;
      int hc = cw ^ (row & 3);
      const float* src = Xa + (size_t)(m0 + row) * Kdim + k0 + hc * 8;
      float4 f0 = *(const float4*)src;
      float4 f1 = *(const float4*)(src + 4);
      union { __bf16 h[8]; uint4 u; } pk;
      pk.h[0] = (__bf16)f0.x; pk.h[1] = (__bf16)f0.y;
      pk.h[2] = (__bf16)f0.z; pk.h[3] = (__bf16)f0.w;
      pk.h[4] = (__bf16)f1.x; pk.h[5] = (__bf16)f1.y;
      pk.h[6] = (__bf16)f1.z; pk.h[7] = (__bf16)f1.w;
      *(uint4*)&As[(size_t)chunk * 8] = pk.u;
    }
    #pragma unroll
    for (int c = 0; c < 2; ++c) {
      int chunk = c * 256 + wave * 64 + lane;
      int row = chunk >> 2;
      int hc = (chunk & 3) ^ (row & 3);
      gload_lds16(Wcat + (size_t)(n0 + row) * Kdim + k0 + hc * 8,
                  &Bs[(size_t)(c * 256 + wave * 64) * 8]);
    }
    __syncthreads();
    bf16x8 af[4], bfr[4];
    #pragma unroll
    for (int m = 0; m < 4; ++m) {
      int rowl = wr * 64 + m * 16 + r;
      af[m] = *(const bf16x8*)&As[rowl * 32 + ((hi ^ (rowl & 3)) * 8)];
    }
    #pragma unroll
    for (int n = 0; n < 4; ++n) {
      int rowl = wc * 64 + n * 16 + r;
      bfr[n] = *(const bf16x8*)&Bs[rowl * 32 + ((hi ^ (rowl & 3)) * 8)];
    }
    #pragma unroll
    for (int m = 0; m < 4; ++m)
      #pragma unroll
      for (int n = 0; n < 4; ++n)
        acc[m][n] = __builtin_amdgcn_mfma_f32_16x16x32_bf16(af[m], bfr[n], acc[m][n], 0, 0, 0);
    __syncthreads();
  }

  const float* bias = proj == 0 ? bq : proj == 1 ? bk : bv;
  if (proj < 2) {
    __bf16* out = proj == 0 ? Qh : Kh;
    const float sc = proj == 0 ? qscale : 1.0f;
    #pragma unroll
    for (int m = 0; m < 4; ++m)
      #pragma unroll
      for (int n = 0; n < 4; ++n)
        #pragma unroll
        for (int rg = 0; rg < 4; ++rg) {
          int row_g = m0 + wr * 64 + m * 16 + hi * 4 + rg;
          int col_g = n0 + wc * 64 + n * 16 + r;
          int c = col_g & 1023, h = c >> 6, d = c & 63;
          int b = row_g >> 11, s = row_g & (Sc - 1);
          float v = (acc[m][n][rg] + bias[c]) * sc;
          out[((((size_t)b * Hc + h) * Sc + s) << 6) + d] = (__bf16)v;
        }
  } else {
    #pragma unroll
    for (int m = 0; m < 4; ++m)
      #pragma unroll
      for (int n = 0; n < 4; ++n) {
        int row0 = m0 + wr * 64 + m * 16 + hi * 4;
        int col_g = n0 + wc * 64 + n * 16 + r;
        int c = col_g & 1023, h = c >> 6, d = c & 63;
        int b = row0 >> 11, s = row0 & (Sc - 1);
        union { __bf16 hh[4]; uint2 u; } w;
        #pragma unroll
        for (int rg = 0; rg < 4; ++rg)
          w.hh[rg] = (__bf16)(acc[m][n][rg] + bias[c]);
        *(uint2*)&Vt[((((size_t)b * Hc + h) * HDc + d) << 11) + s] = w.u;
      }
  }
}

// ---------------- out-projection GEMM ----------------
__global__ __launch_bounds__(256, 2)
void gemm_out(const __bf16* __restrict__ A, const __bf16* __restrict__ Bw,
              const float* __restrict__ bias, float* __restrict__ outp)
{
  __shared__ __align__(16) __bf16 As[128 * 32];
  __shared__ __align__(16) __bf16 Bs[128 * 32];
  const int tid = threadIdx.x;
  const int wave = tid >> 6, lane = tid & 63;
  const int wr = wave >> 1, wc = wave & 1;
  const int r = lane & 15, hi = lane >> 4;
  // XCD swizzle: 8 M-panels per XCD, 8 n-blocks each.
  const int lin = (int)blockIdx.y * 8 + (int)blockIdx.x;    // 0..511
  const int xcd = lin & 7, s8 = lin >> 3;                   // 0..63
  const int m0 = (((xcd << 3) | (s8 >> 3)) ) * 128;
  const int n0 = (s8 & 7) * 128;

  f32x4 acc[4][4] = {};

  for (int k0 = 0; k0 < Kdim; k0 += 32) {
    #pragma unroll
    for (int c = 0; c < 2; ++c) {
      int chunk = c * 256 + wave * 64 + lane;
      int row = chunk >> 2;
      int hc = (chunk & 3) ^ (row & 3);
      gload_lds16(A  + (size_t)(m0 + row) * Kdim + k0 + hc * 8,
                  &As[(size_t)(c * 256 + wave * 64) * 8]);
      gload_lds16(Bw + (size_t)(n0 + row) * Kdim + k0 + hc * 8,
                  &Bs[(size_t)(c * 256 + wave * 64) * 8]);
    }
    __syncthreads();
    bf16x8 af[4], bfr[4];
    #pragma unroll
    for (int m = 0; m < 4; ++m) {
      int rowl = wr * 64 + m * 16 + r;
      af[m] = *(const bf16x8*)&As[rowl * 32 + ((hi ^ (rowl & 3)) * 8)];
    }
    #pragma unroll
    for (int n = 0; n < 4; ++n) {
      int rowl = wc * 64 + n * 16 + r;
      bfr[n] = *(const bf16x8*)&Bs[rowl * 32 + ((hi ^ (rowl & 3)) * 8)];
    }
    #pragma unroll
    for (int m = 0; m < 4; ++m)
      #pragma unroll
      for (int n = 0; n < 4; ++n)
        acc[m][n] = __builtin_amdgcn_mfma_f32_16x16x32_bf16(af[m], bfr[n], acc[m][n], 0, 0, 0);
    __syncthreads();
  }

  #pragma unroll
  for (int m = 0; m < 4; ++m)
    #pragma unroll
    for (int n = 0; n < 4; ++n)
      #pragma unroll
      for (int rg = 0; rg < 4; ++rg) {
        int row_g = m0 + wr * 64 + m * 16 + hi * 4 + rg;
        int col_g = n0 + wc * 64 + n * 16 + r;
        outp[(size_t)row_g * Dc + col_g] = acc[m][n][rg] + bias[col_g];
      }
}

// ---------------- causal flash attention, split-KV (R6-proven body) ----------
// Qh/Kh: [B*H][S][64] bf16 (Q pre-scaled by log2e/8 -> log2-domain softmax).
// Vt: [B*H][64][S] bf16. out: [B][S][D] bf16.
// XCD swizzle: all 32 q-tiles of one bh on one XCD (K/V L2-resident: 8 bh x
// 512KB = 4MB per XCD L2). Longest q-tiles first within each bh.
__global__ __launch_bounds__(128, 2)
void attn_causal(const __bf16* __restrict__ Qh, const __bf16* __restrict__ Kh,
                 const __bf16* __restrict__ Vt, __bf16* __restrict__ outp)
{
  __shared__ __align__(16) float OaS[4][4][64][4];  // 16 KB (wave1 partial O^T)
  __shared__ float MS[4][64];                        // 1 KB
  __shared__ float LS[4][64];                        // 1 KB

  const int tid = threadIdx.x;
  const int wave = tid >> 6, lane = tid & 63;
  const int r = lane & 15, hi = lane >> 4;
  // bijective remap: lin -> (xcd, s); bh = xcd*8 + s>>5, qt = 31-(s&31).
  const int lin = (int)blockIdx.y * 32 + (int)blockIdx.x;   // 0..2047
  const int xcd = lin & 7, s8 = lin >> 3;                   // s8: 0..255
  const int bh = (xcd << 3) | (s8 >> 5);                    // 0..63
  const int qt = 31 - (s8 & 31);                            // longest first
  const int q0 = qt * 64;
  const __bf16* Q = Qh + (size_t)bh * (Sc * HDc);
  const __bf16* K = Kh + (size_t)bh * (Sc * HDc);
  const __bf16* V = Vt + (size_t)bh * (HDc * Sc);

  // Q fragments (B-operand: col=r, k=hi*8+j per 32-chunk)
  bf16x8 qf[4][2];
  #pragma unroll
  for (int m = 0; m < 4; ++m)
    #pragma unroll
    for (int kc = 0; kc < 2; ++kc)
      qf[m][kc] = *(const bf16x8*)&Q[(size_t)(q0 + m * 16 + r) * 64 + kc * 32 + hi * 8];

  f32x4 o_acc[4][4] = {};   // O^T: row hd = n*16+hi*4+rg, col q = m*16+r
  float mrow[4], lrow[4];
  #pragma unroll
  for (int m = 0; m < 4; ++m) { mrow[m] = -1e30f; lrow[m] = 0.f; }

  const int T = qt + 1;
  const int half = (T + 1) >> 1;
  const int t0 = wave ? half : 0;
  const int t1 = wave ? T : half;

  bf16x8 kf[4][2], vf[4][2], pb[4][2];

  // preload first tile of this wave's range (in-bounds even if range empty)
  #pragma unroll
  for (int n = 0; n < 4; ++n)
    #pragma unroll
    for (int kc = 0; kc < 2; ++kc) {
      kf[n][kc] = *(const bf16x8*)&K[(size_t)(t0 * 64 + n * 16 + r) * 64 + kc * 32 + hi * 8];
      vf[n][kc] = *(const bf16x8*)&V[(size_t)(n * 16 + r) * Sc + t0 * 64 + kc * 32 + hi * 8];
    }

  for (int t = t0; t < t1; ++t) {
    const bool diag = (t == T - 1);
    const int kvn = (t + 1) * 64;

    // ---- phase 1: QK^T (swapped) + log2-softmax + in-register P exchange ----
    #pragma unroll
    for (int m = 0; m < 4; ++m) {
      f32x4 sn[4];
      __builtin_amdgcn_s_setprio(1);
      #pragma unroll
      for (int n = 0; n < 4; ++n) {
        f32x4 z = {0.f, 0.f, 0.f, 0.f};
        sn[n] = __builtin_amdgcn_mfma_f32_16x16x32_bf16(kf[n][0], qf[m][0], z, 0, 0, 0);
        sn[n] = __builtin_amdgcn_mfma_f32_16x16x32_bf16(kf[n][1], qf[m][1], sn[n], 0, 0, 0);
      }
      __builtin_amdgcn_s_setprio(0);
      if (diag) {
        #pragma unroll
        for (int n = 0; n < 4; ++n)
          #pragma unroll
          for (int rg = 0; rg < 4; ++rg)
            if (n * 16 + hi * 4 + rg > m * 16 + r) sn[n][rg] = -1e30f;
      }
      float mx = fmaxf(fmaxf(fmaxf(sn[0][0], sn[0][1]), fmaxf(sn[0][2], sn[0][3])),
                       fmaxf(fmaxf(sn[1][0], sn[1][1]), fmaxf(sn[1][2], sn[1][3])));
      mx = fmaxf(mx, fmaxf(fmaxf(fmaxf(sn[2][0], sn[2][1]), fmaxf(sn[2][2], sn[2][3])),
                           fmaxf(fmaxf(sn[3][0], sn[3][1]), fmaxf(sn[3][2], sn[3][3]))));
      mx = fmaxf(mx, __shfl_xor(mx, 16));
      mx = fmaxf(mx, __shfl_xor(mx, 32));
      float mloc = mrow[m];
      if (__any(mx > mloc + 8.f)) {          // T13 defer-max (log2 domain)
        float mnew = fmaxf(mloc, mx);
        float sc = __builtin_exp2f(mloc - mnew);
        lrow[m] *= sc;
        #pragma unroll
        for (int n = 0; n < 4; ++n) o_acc[m][n] *= sc;
        mrow[m] = mnew; mloc = mnew;
      }
      float rs = 0.f;
      #pragma unroll
      for (int n = 0; n < 4; ++n)
        #pragma unroll
        for (int rg = 0; rg < 4; ++rg) {
          float p = __builtin_exp2f(sn[n][rg] - mloc);
          sn[n][rg] = p;
          rs += p;
        }
      rs += __shfl_xor(rs, 16);
      rs += __shfl_xor(rs, 32);
      lrow[m] += rs;

      // exchange P^T -> B-operand layout (R3-proven: perm32 + xor16 + select).
      #pragma unroll
      for (int kc = 0; kc < 2; ++kc) {
        uint32_t p0a, p0b, p1a, p1b;
        asm("v_cvt_pk_bf16_f32 %0, %1, %2" : "=v"(p0a) : "v"(sn[2*kc][0]),   "v"(sn[2*kc][1]));
        asm("v_cvt_pk_bf16_f32 %0, %1, %2" : "=v"(p0b) : "v"(sn[2*kc][2]),   "v"(sn[2*kc][3]));
        asm("v_cvt_pk_bf16_f32 %0, %1, %2" : "=v"(p1a) : "v"(sn[2*kc+1][0]), "v"(sn[2*kc+1][1]));
        asm("v_cvt_pk_bf16_f32 %0, %1, %2" : "=v"(p1b) : "v"(sn[2*kc+1][2]), "v"(sn[2*kc+1][3]));
        asm("v_permlane32_swap_b32 %0, %1" : "+v"(p0a), "+v"(p1a));
        asm("v_permlane32_swap_b32 %0, %1" : "+v"(p0b), "+v"(p1b));
        uint32_t Xa = (uint32_t)__shfl_xor((int)p1a, 16);
        uint32_t Xb = (uint32_t)__shfl_xor((int)p1b, 16);
        uint32_t Ya = (uint32_t)__shfl_xor((int)p0a, 16);
        uint32_t Yb = (uint32_t)__shfl_xor((int)p0b, 16);
        union { uint32_t u[4]; bf16x8 v; } pk;
        pk.u[0] = (hi & 1) ? Xa : p0a;
        pk.u[1] = (hi & 1) ? Xb : p0b;
        pk.u[2] = (hi & 1) ? p1a : Ya;
        pk.u[3] = (hi & 1) ? p1b : Yb;
        pb[m][kc] = pk.v;
      }
    }

    // prefetch next K tile (kf dead after phase 1)
    if (t + 1 < t1) {
      #pragma unroll
      for (int n = 0; n < 4; ++n)
        #pragma unroll
        for (int kc = 0; kc < 2; ++kc)
          kf[n][kc] = *(const bf16x8*)&K[(size_t)(kvn + n * 16 + r) * 64 + kc * 32 + hi * 8];
    }

    // ---- phase 2: PV (swapped: O^T += V^T-frag * P-frag) ----
    __builtin_amdgcn_s_setprio(1);
    #pragma unroll
    for (int m = 0; m < 4; ++m)
      #pragma unroll
      for (int n = 0; n < 4; ++n) {
        o_acc[m][n] = __builtin_amdgcn_mfma_f32_16x16x32_bf16(vf[n][0], pb[m][0], o_acc[m][n], 0, 0, 0);
        o_acc[m][n] = __builtin_amdgcn_mfma_f32_16x16x32_bf16(vf[n][1], pb[m][1], o_acc[m][n], 0, 0, 0);
      }
    __builtin_amdgcn_s_setprio(0);

    // prefetch next V tile (vf dead after phase 2)
    if (t + 1 < t1) {
      #pragma unroll
      for (int n = 0; n < 4; ++n)
        #pragma unroll
        for (int kc = 0; kc < 2; ++kc)
          vf[n][kc] = *(const bf16x8*)&V[(size_t)(n * 16 + r) * Sc + kvn + kc * 32 + hi * 8];
    }
  }

  // ---- merge wave1 partial into wave0, then epilogue ----
  if (wave == 1) {
    #pragma unroll
    for (int m = 0; m < 4; ++m) {
      MS[m][lane] = mrow[m];
      LS[m][lane] = lrow[m];
      #pragma unroll
      for (int n = 0; n < 4; ++n)
        *(f32x4*)OaS[m][n][lane] = o_acc[m][n];
    }
  }
  __syncthreads();
  if (wave == 0) {
    const int b = bh >> 4, h = bh & 15;
    #pragma unroll
    for (int m = 0; m < 4; ++m) {
      float mB = MS[m][lane], lB = LS[m][lane];
      float mF = fmaxf(mrow[m], mB);
      float aA = __builtin_exp2f(mrow[m] - mF);
      float aB = __builtin_exp2f(mB - mF);
      float inv = 1.f / (lrow[m] * aA + lB * aB);
      size_t row = (size_t)b * Sc + q0 + m * 16 + r;
      #pragma unroll
      for (int n = 0; n < 4; ++n) {
        f32x4 oB = *(f32x4*)OaS[m][n][lane];
        union { __bf16 hh[4]; uint2 u; } w;
        #pragma unroll
        for (int rg = 0; rg < 4; ++rg)
          w.hh[rg] = (__bf16)((o_acc[m][n][rg] * aA + oB[rg] * aB) * inv);
        int col = h * 64 + n * 16 + hi * 4;
        *(uint2*)&outp[row * Dc + col] = w.u;
      }
    }
  }
}

// ---------------- launch ----------------
extern "C" void kernel_launch(void* const* d_in, const int* in_sizes, int n_in,
                              void* d_out, int out_size, void* d_ws, size_t ws_size,
                              hipStream_t stream) {
  const float* q  = (const float*)d_in[0];
  const float* k  = (const float*)d_in[1];
  const float* v  = (const float*)d_in[2];
  const float* Wq = (const float*)d_in[4];
  const float* bq = (const float*)d_in[5];
  const float* Wk = (const float*)d_in[6];
  const float* bk = (const float*)d_in[7];
  const float* Wv = (const float*)d_in[8];
  const float* bv = (const float*)d_in[9];
  const float* Wo = (const float*)d_in[10];
  const float* bo = (const float*)d_in[11];

  char* ws = (char*)d_ws;
  constexpr size_t MB = 1u << 20;
  __bf16* Wcat = (__bf16*)(ws + 0 * MB);   // Wq|Wk|Wv rows, 6 MB
  __bf16* Wkb  = (__bf16*)(ws + 2 * MB);
  __bf16* Wvb  = (__bf16*)(ws + 4 * MB);
  __bf16* Wob  = (__bf16*)(ws + 6 * MB);
  __bf16* Xbf  = (__bf16*)(ws + 8 * MB);   // attn out, 16 MB
  __bf16* QhB  = (__bf16*)(ws + 24 * MB);
  __bf16* KhB  = (__bf16*)(ws + 40 * MB);
  __bf16* VtB  = (__bf16*)(ws + 56 * MB);  // V^T: [B*H][64][S]

  const int nW4 = (Dc * Dc) / 4;           // 262144
  cvt4_f32_to_bf16<<<(4 * nW4) / 256, 256, 0, stream>>>(Wq, Wk, Wv, Wo, Wcat, Wkb, Wvb, Wob, nW4);

  const float qscale = 0.125f * 1.44269504f;  // fold 1/sqrt(64) and log2(e)
  gemm_qkv<<<dim3(24, Mrows / 128), 256, 0, stream>>>(q, k, v, Wcat, bq, bk, bv,
                                                      QhB, KhB, VtB, qscale);

  attn_causal<<<dim3(32, Bc * Hc), 128, 0, stream>>>(QhB, KhB, VtB, Xbf);

  gemm_out<<<dim3(8, Mrows / 128), 256, 0, stream>>>(Xbf, Wob, bo, (float*)d_out);
}

// Round 11
// 267.050 us; speedup vs baseline: 3.1662x; 1.0458x over previous
//
#include <hip/hip_runtime.h>
#include <hip/hip_bf16.h>
#include <cstdint>
#include <cstddef>

typedef __attribute__((ext_vector_type(4))) float f32x4;
typedef __attribute__((ext_vector_type(8))) __bf16 bf16x8;

constexpr int Bc = 4, Sc = 2048, Dc = 1024, Hc = 16, HDc = 64;
constexpr int Mrows = Bc * Sc;   // 8192
constexpr int Kdim = Dc;         // 1024

__device__ __forceinline__ void gload_lds16(const void* g, void* lds) {
  __builtin_amdgcn_global_load_lds(
      (const __attribute__((address_space(1))) void*)g,
      (__attribute__((address_space(3))) void*)lds, 16, 0, 0);
}

// ---------------- fp32 -> bf16 weight converts (one fused launch) ----------------
__global__ void cvt4_f32_to_bf16(const float* __restrict__ s0, const float* __restrict__ s1,
                                 const float* __restrict__ s2, const float* __restrict__ s3,
                                 __bf16* __restrict__ d0, __bf16* __restrict__ d1,
                                 __bf16* __restrict__ d2, __bf16* __restrict__ d3, int n4each) {
  int i = blockIdx.x * blockDim.x + threadIdx.x;
  int which = i / n4each, j = i - which * n4each;
  const float* s = which == 0 ? s0 : which == 1 ? s1 : which == 2 ? s2 : s3;
  __bf16* d = which == 0 ? d0 : which == 1 ? d1 : which == 2 ? d2 : d3;
  float4 f = ((const float4*)s)[j];
  union { __bf16 h[4]; uint2 u; } p;
  p.h[0] = (__bf16)f.x; p.h[1] = (__bf16)f.y;
  p.h[2] = (__bf16)f.z; p.h[3] = (__bf16)f.w;
  ((uint2*)d)[j] = p.u;
}

// ---------------- fused QKV GEMM (R10-proven) ----------------
__global__ __launch_bounds__(256, 2)
void gemm_qkv(const float* __restrict__ qin, const float* __restrict__ kin,
              const float* __restrict__ vin, const __bf16* __restrict__ Wcat,
              const float* __restrict__ bq, const float* __restrict__ bk,
              const float* __restrict__ bv,
              __bf16* __restrict__ Qh, __bf16* __restrict__ Kh,
              __bf16* __restrict__ Vt, float qscale)
{
  __shared__ __align__(16) __bf16 As[128 * 32];
  __shared__ __align__(16) __bf16 Bs[128 * 32];
  const int tid = threadIdx.x;
  const int wave = tid >> 6, lane = tid & 63;
  const int wr = wave >> 1, wc = wave & 1;
  const int r = lane & 15, hi = lane >> 4;
  const int lin = (int)blockIdx.y * 24 + (int)blockIdx.x;   // 0..1535
  const int xcd = lin & 7, s8 = lin >> 3;                   // s8: 0..191
  const int my = (xcd << 3) | (s8 / 24);                    // 0..63
  const int mx = s8 % 24;                                   // 0..23
  const int m0 = my * 128, n0 = mx * 128;
  const int proj = n0 >> 10;                       // block-uniform: 0=Q 1=K 2=V
  const float* Xa = proj == 0 ? qin : proj == 1 ? kin : vin;

  f32x4 acc[4][4] = {};

  for (int k0 = 0; k0 < Kdim; k0 += 32) {
    #pragma unroll
    for (int c = 0; c < 2; ++c) {
      int chunk = c * 256 + tid;
      int row = chunk >> 2;
      int cw = chunk & 3;
      int hc = cw ^ (row & 3);
      const float* src = Xa + (size_t)(m0 + row) * Kdim + k0 + hc * 8;
      float4 f0 = *(const float4*)src;
      float4 f1 = *(const float4*)(src + 4);
      union { __bf16 h[8]; uint4 u; } pk;
      pk.h[0] = (__bf16)f0.x; pk.h[1] = (__bf16)f0.y;
      pk.h[2] = (__bf16)f0.z; pk.h[3] = (__bf16)f0.w;
      pk.h[4] = (__bf16)f1.x; pk.h[5] = (__bf16)f1.y;
      pk.h[6] = (__bf16)f1.z; pk.h[7] = (__bf16)f1.w;
      *(uint4*)&As[(size_t)chunk * 8] = pk.u;
    }
    #pragma unroll
    for (int c = 0; c < 2; ++c) {
      int chunk = c * 256 + wave * 64 + lane;
      int row = chunk >> 2;
      int hc = (chunk & 3) ^ (row & 3);
      gload_lds16(Wcat + (size_t)(n0 + row) * Kdim + k0 + hc * 8,
                  &Bs[(size_t)(c * 256 + wave * 64) * 8]);
    }
    __syncthreads();
    bf16x8 af[4], bfr[4];
    #pragma unroll
    for (int m = 0; m < 4; ++m) {
      int rowl = wr * 64 + m * 16 + r;
      af[m] = *(const bf16x8*)&As[rowl * 32 + ((hi ^ (rowl & 3)) * 8)];
    }
    #pragma unroll
    for (int n = 0; n < 4; ++n) {
      int rowl = wc * 64 + n * 16 + r;
      bfr[n] = *(const bf16x8*)&Bs[rowl * 32 + ((hi ^ (rowl & 3)) * 8)];
    }
    #pragma unroll
    for (int m = 0; m < 4; ++m)
      #pragma unroll
      for (int n = 0; n < 4; ++n)
        acc[m][n] = __builtin_amdgcn_mfma_f32_16x16x32_bf16(af[m], bfr[n], acc[m][n], 0, 0, 0);
    __syncthreads();
  }

  const float* bias = proj == 0 ? bq : proj == 1 ? bk : bv;
  if (proj < 2) {
    __bf16* out = proj == 0 ? Qh : Kh;
    const float sc = proj == 0 ? qscale : 1.0f;
    #pragma unroll
    for (int m = 0; m < 4; ++m)
      #pragma unroll
      for (int n = 0; n < 4; ++n)
        #pragma unroll
        for (int rg = 0; rg < 4; ++rg) {
          int row_g = m0 + wr * 64 + m * 16 + hi * 4 + rg;
          int col_g = n0 + wc * 64 + n * 16 + r;
          int c = col_g & 1023, h = c >> 6, d = c & 63;
          int b = row_g >> 11, s = row_g & (Sc - 1);
          float v = (acc[m][n][rg] + bias[c]) * sc;
          out[((((size_t)b * Hc + h) * Sc + s) << 6) + d] = (__bf16)v;
        }
  } else {
    #pragma unroll
    for (int m = 0; m < 4; ++m)
      #pragma unroll
      for (int n = 0; n < 4; ++n) {
        int row0 = m0 + wr * 64 + m * 16 + hi * 4;
        int col_g = n0 + wc * 64 + n * 16 + r;
        int c = col_g & 1023, h = c >> 6, d = c & 63;
        int b = row0 >> 11, s = row0 & (Sc - 1);
        union { __bf16 hh[4]; uint2 u; } w;
        #pragma unroll
        for (int rg = 0; rg < 4; ++rg)
          w.hh[rg] = (__bf16)(acc[m][n][rg] + bias[c]);
        *(uint2*)&Vt[((((size_t)b * Hc + h) * HDc + d) << 11) + s] = w.u;
      }
  }
}

// ---------------- out-projection GEMM (R10-proven) ----------------
__global__ __launch_bounds__(256, 2)
void gemm_out(const __bf16* __restrict__ A, const __bf16* __restrict__ Bw,
              const float* __restrict__ bias, float* __restrict__ outp)
{
  __shared__ __align__(16) __bf16 As[128 * 32];
  __shared__ __align__(16) __bf16 Bs[128 * 32];
  const int tid = threadIdx.x;
  const int wave = tid >> 6, lane = tid & 63;
  const int wr = wave >> 1, wc = wave & 1;
  const int r = lane & 15, hi = lane >> 4;
  const int lin = (int)blockIdx.y * 8 + (int)blockIdx.x;    // 0..511
  const int xcd = lin & 7, s8 = lin >> 3;                   // 0..63
  const int m0 = (((xcd << 3) | (s8 >> 3)) ) * 128;
  const int n0 = (s8 & 7) * 128;

  f32x4 acc[4][4] = {};

  for (int k0 = 0; k0 < Kdim; k0 += 32) {
    #pragma unroll
    for (int c = 0; c < 2; ++c) {
      int chunk = c * 256 + wave * 64 + lane;
      int row = chunk >> 2;
      int hc = (chunk & 3) ^ (row & 3);
      gload_lds16(A  + (size_t)(m0 + row) * Kdim + k0 + hc * 8,
                  &As[(size_t)(c * 256 + wave * 64) * 8]);
      gload_lds16(Bw + (size_t)(n0 + row) * Kdim + k0 + hc * 8,
                  &Bs[(size_t)(c * 256 + wave * 64) * 8]);
    }
    __syncthreads();
    bf16x8 af[4], bfr[4];
    #pragma unroll
    for (int m = 0; m < 4; ++m) {
      int rowl = wr * 64 + m * 16 + r;
      af[m] = *(const bf16x8*)&As[rowl * 32 + ((hi ^ (rowl & 3)) * 8)];
    }
    #pragma unroll
    for (int n = 0; n < 4; ++n) {
      int rowl = wc * 64 + n * 16 + r;
      bfr[n] = *(const bf16x8*)&Bs[rowl * 32 + ((hi ^ (rowl & 3)) * 8)];
    }
    #pragma unroll
    for (int m = 0; m < 4; ++m)
      #pragma unroll
      for (int n = 0; n < 4; ++n)
        acc[m][n] = __builtin_amdgcn_mfma_f32_16x16x32_bf16(af[m], bfr[n], acc[m][n], 0, 0, 0);
    __syncthreads();
  }

  #pragma unroll
  for (int m = 0; m < 4; ++m)
    #pragma unroll
    for (int n = 0; n < 4; ++n)
      #pragma unroll
      for (int rg = 0; rg < 4; ++rg) {
        int row_g = m0 + wr * 64 + m * 16 + hi * 4 + rg;
        int col_g = n0 + wc * 64 + n * 16 + r;
        outp[(size_t)row_g * Dc + col_g] = acc[m][n][rg] + bias[col_g];
      }
}

// ---------------- causal flash attention: lean independent waves ----------
// Each wave owns 32 q-rows (qh in 0..63) and its FULL causal KV range.
// Pairing qh=px (wave0) with qh=63-px (wave1) makes every block exactly 33
// tile-units. No LDS, no barriers, no merge. All per-tile arithmetic is
// byte-identical to the R10-passing kernel (m-loop is 2 instead of 4).
// Qh/Kh: [B*H][S][64] bf16 (Q pre-scaled by log2e/8). Vt: [B*H][64][S].
__global__ __launch_bounds__(128, 2)
void attn_causal(const __bf16* __restrict__ Qh, const __bf16* __restrict__ Kh,
                 const __bf16* __restrict__ Vt, __bf16* __restrict__ outp)
{
  const int tid = threadIdx.x;
  const int wave = tid >> 6, lane = tid & 63;
  const int r = lane & 15, hi = lane >> 4;
  // XCD swizzle: all 32 blocks of one bh on one XCD (K/V L2-resident).
  const int lin = (int)blockIdx.y * 32 + (int)blockIdx.x;   // 0..2047
  const int xcd = lin & 7, s8 = lin >> 3;                   // s8: 0..255
  const int bh = (xcd << 3) | (s8 >> 5);                    // 0..63
  const int px = s8 & 31;                                   // 0..31
  const int qh = wave ? (63 - px) : px;                     // paired balance
  const int q0 = qh * 32;
  const __bf16* Q = Qh + (size_t)bh * (Sc * HDc);
  const __bf16* K = Kh + (size_t)bh * (Sc * HDc);
  const __bf16* V = Vt + (size_t)bh * (HDc * Sc);

  // Q fragments (B-operand: col=r, k=hi*8+j per 32-chunk), 32 rows
  bf16x8 qf[2][2];
  #pragma unroll
  for (int m = 0; m < 2; ++m)
    #pragma unroll
    for (int kc = 0; kc < 2; ++kc)
      qf[m][kc] = *(const bf16x8*)&Q[(size_t)(q0 + m * 16 + r) * 64 + kc * 32 + hi * 8];

  f32x4 o_acc[2][4] = {};   // O^T: row hd = n*16+hi*4+rg, col q = m*16+r
  float mrow[2], lrow[2];
  #pragma unroll
  for (int m = 0; m < 2; ++m) { mrow[m] = -1e30f; lrow[m] = 0.f; }

  const int T = (qh >> 1) + 1;
  const int qloc_base = (qh & 1) * 32;   // q offset within the diag kv-tile

  bf16x8 kf[4][2], vf[4][2], pb[2][2];

  // preload tile 0
  #pragma unroll
  for (int n = 0; n < 4; ++n)
    #pragma unroll
    for (int kc = 0; kc < 2; ++kc) {
      kf[n][kc] = *(const bf16x8*)&K[(size_t)(n * 16 + r) * 64 + kc * 32 + hi * 8];
      vf[n][kc] = *(const bf16x8*)&V[(size_t)(n * 16 + r) * Sc + kc * 32 + hi * 8];
    }

  for (int t = 0; t < T; ++t) {
    const bool diag = (t == T - 1);
    const int kvn = (t + 1) * 64;

    // ---- phase 1: QK^T (swapped) + log2-softmax + in-register P exchange ----
    #pragma unroll
    for (int m = 0; m < 2; ++m) {
      f32x4 sn[4];
      __builtin_amdgcn_s_setprio(1);
      #pragma unroll
      for (int n = 0; n < 4; ++n) {
        f32x4 z = {0.f, 0.f, 0.f, 0.f};
        sn[n] = __builtin_amdgcn_mfma_f32_16x16x32_bf16(kf[n][0], qf[m][0], z, 0, 0, 0);
        sn[n] = __builtin_amdgcn_mfma_f32_16x16x32_bf16(kf[n][1], qf[m][1], sn[n], 0, 0, 0);
      }
      __builtin_amdgcn_s_setprio(0);
      if (diag) {
        #pragma unroll
        for (int n = 0; n < 4; ++n)
          #pragma unroll
          for (int rg = 0; rg < 4; ++rg)
            if (n * 16 + hi * 4 + rg > qloc_base + m * 16 + r) sn[n][rg] = -1e30f;
      }
      float mx = fmaxf(fmaxf(fmaxf(sn[0][0], sn[0][1]), fmaxf(sn[0][2], sn[0][3])),
                       fmaxf(fmaxf(sn[1][0], sn[1][1]), fmaxf(sn[1][2], sn[1][3])));
      mx = fmaxf(mx, fmaxf(fmaxf(fmaxf(sn[2][0], sn[2][1]), fmaxf(sn[2][2], sn[2][3])),
                           fmaxf(fmaxf(sn[3][0], sn[3][1]), fmaxf(sn[3][2], sn[3][3]))));
      mx = fmaxf(mx, __shfl_xor(mx, 16));
      mx = fmaxf(mx, __shfl_xor(mx, 32));
      float mloc = mrow[m];
      if (__any(mx > mloc + 8.f)) {          // T13 defer-max (log2 domain)
        float mnew = fmaxf(mloc, mx);
        float sc = __builtin_exp2f(mloc - mnew);
        lrow[m] *= sc;
        #pragma unroll
        for (int n = 0; n < 4; ++n) o_acc[m][n] *= sc;
        mrow[m] = mnew; mloc = mnew;
      }
      float rs = 0.f;
      #pragma unroll
      for (int n = 0; n < 4; ++n)
        #pragma unroll
        for (int rg = 0; rg < 4; ++rg) {
          float p = __builtin_exp2f(sn[n][rg] - mloc);
          sn[n][rg] = p;
          rs += p;
        }
      rs += __shfl_xor(rs, 16);
      rs += __shfl_xor(rs, 32);
      lrow[m] += rs;

      // exchange P^T -> B-operand layout (R3/R10-proven: perm32 + xor16 + select)
      #pragma unroll
      for (int kc = 0; kc < 2; ++kc) {
        uint32_t p0a, p0b, p1a, p1b;
        asm("v_cvt_pk_bf16_f32 %0, %1, %2" : "=v"(p0a) : "v"(sn[2*kc][0]),   "v"(sn[2*kc][1]));
        asm("v_cvt_pk_bf16_f32 %0, %1, %2" : "=v"(p0b) : "v"(sn[2*kc][2]),   "v"(sn[2*kc][3]));
        asm("v_cvt_pk_bf16_f32 %0, %1, %2" : "=v"(p1a) : "v"(sn[2*kc+1][0]), "v"(sn[2*kc+1][1]));
        asm("v_cvt_pk_bf16_f32 %0, %1, %2" : "=v"(p1b) : "v"(sn[2*kc+1][2]), "v"(sn[2*kc+1][3]));
        asm("v_permlane32_swap_b32 %0, %1" : "+v"(p0a), "+v"(p1a));
        asm("v_permlane32_swap_b32 %0, %1" : "+v"(p0b), "+v"(p1b));
        uint32_t Xa = (uint32_t)__shfl_xor((int)p1a, 16);
        uint32_t Xb = (uint32_t)__shfl_xor((int)p1b, 16);
        uint32_t Ya = (uint32_t)__shfl_xor((int)p0a, 16);
        uint32_t Yb = (uint32_t)__shfl_xor((int)p0b, 16);
        union { uint32_t u[4]; bf16x8 v; } pk;
        pk.u[0] = (hi & 1) ? Xa : p0a;
        pk.u[1] = (hi & 1) ? Xb : p0b;
        pk.u[2] = (hi & 1) ? p1a : Ya;
        pk.u[3] = (hi & 1) ? p1b : Yb;
        pb[m][kc] = pk.v;
      }
    }

    // prefetch next K tile (kf dead after phase 1)
    if (t + 1 < T) {
      #pragma unroll
      for (int n = 0; n < 4; ++n)
        #pragma unroll
        for (int kc = 0; kc < 2; ++kc)
          kf[n][kc] = *(const bf16x8*)&K[(size_t)(kvn + n * 16 + r) * 64 + kc * 32 + hi * 8];
    }

    // ---- phase 2: PV (swapped: O^T += V^T-frag * P-frag) ----
    __builtin_amdgcn_s_setprio(1);
    #pragma unroll
    for (int m = 0; m < 2; ++m)
      #pragma unroll
      for (int n = 0; n < 4; ++n) {
        o_acc[m][n] = __builtin_amdgcn_mfma_f32_16x16x32_bf16(vf[n][0], pb[m][0], o_acc[m][n], 0, 0, 0);
        o_acc[m][n] = __builtin_amdgcn_mfma_f32_16x16x32_bf16(vf[n][1], pb[m][1], o_acc[m][n], 0, 0, 0);
      }
    __builtin_amdgcn_s_setprio(0);

    // prefetch next V tile (vf dead after phase 2)
    if (t + 1 < T) {
      #pragma unroll
      for (int n = 0; n < 4; ++n)
        #pragma unroll
        for (int kc = 0; kc < 2; ++kc)
          vf[n][kc] = *(const bf16x8*)&V[(size_t)(n * 16 + r) * Sc + kvn + kc * 32 + hi * 8];
    }
  }

  // ---- epilogue: independent per wave ----
  const int b = bh >> 4, h = bh & 15;
  #pragma unroll
  for (int m = 0; m < 2; ++m) {
    float inv = 1.f / lrow[m];
    size_t row = (size_t)b * Sc + q0 + m * 16 + r;
    #pragma unroll
    for (int n = 0; n < 4; ++n) {
      union { __bf16 hh[4]; uint2 u; } w;
      #pragma unroll
      for (int rg = 0; rg < 4; ++rg)
        w.hh[rg] = (__bf16)(o_acc[m][n][rg] * inv);
      int col = h * 64 + n * 16 + hi * 4;
      *(uint2*)&outp[row * Dc + col] = w.u;
    }
  }
}

// ---------------- launch ----------------
extern "C" void kernel_launch(void* const* d_in, const int* in_sizes, int n_in,
                              void* d_out, int out_size, void* d_ws, size_t ws_size,
                              hipStream_t stream) {
  const float* q  = (const float*)d_in[0];
  const float* k  = (const float*)d_in[1];
  const float* v  = (const float*)d_in[2];
  const float* Wq = (const float*)d_in[4];
  const float* bq = (const float*)d_in[5];
  const float* Wk = (const float*)d_in[6];
  const float* bk = (const float*)d_in[7];
  const float* Wv = (const float*)d_in[8];
  const float* bv = (const float*)d_in[9];
  const float* Wo = (const float*)d_in[10];
  const float* bo = (const float*)d_in[11];

  char* ws = (char*)d_ws;
  constexpr size_t MB = 1u << 20;
  __bf16* Wcat = (__bf16*)(ws + 0 * MB);   // Wq|Wk|Wv rows, 6 MB
  __bf16* Wkb  = (__bf16*)(ws + 2 * MB);
  __bf16* Wvb  = (__bf16*)(ws + 4 * MB);
  __bf16* Wob  = (__bf16*)(ws + 6 * MB);
  __bf16* Xbf  = (__bf16*)(ws + 8 * MB);   // attn out, 16 MB
  __bf16* QhB  = (__bf16*)(ws + 24 * MB);
  __bf16* KhB  = (__bf16*)(ws + 40 * MB);
  __bf16* VtB  = (__bf16*)(ws + 56 * MB);  // V^T: [B*H][64][S]

  const int nW4 = (Dc * Dc) / 4;           // 262144
  cvt4_f32_to_bf16<<<(4 * nW4) / 256, 256, 0, stream>>>(Wq, Wk, Wv, Wo, Wcat, Wkb, Wvb, Wob, nW4);

  const float qscale = 0.125f * 1.44269504f;  // fold 1/sqrt(64) and log2(e)
  gemm_qkv<<<dim3(24, Mrows / 128), 256, 0, stream>>>(q, k, v, Wcat, bq, bk, bv,
                                                      QhB, KhB, VtB, qscale);

  attn_causal<<<dim3(32, Bc * Hc), 128, 0, stream>>>(QhB, KhB, VtB, Xbf);

  gemm_out<<<dim3(8, Mrows / 128), 256, 0, stream>>>(Xbf, Wob, bo, (float*)d_out);
}

// Round 12
// 238.585 us; speedup vs baseline: 3.5439x; 1.1193x over previous
//
#include <hip/hip_runtime.h>
#include <hip/hip_bf16.h>
#include <cstdint>
#include <cstddef>

typedef __attribute__((ext_vector_type(4))) float f32x4;
typedef __attribute__((ext_vector_type(16))) float f32x16;
typedef __attribute__((ext_vector_type(8))) __bf16 bf16x8;

constexpr int Bc = 4, Sc = 2048, Dc = 1024, Hc = 16, HDc = 64;
constexpr int Mrows = Bc * Sc;   // 8192
constexpr int Kdim = Dc;         // 1024

__device__ __forceinline__ void gload_lds16(const void* g, void* lds) {
  __builtin_amdgcn_global_load_lds(
      (const __attribute__((address_space(1))) void*)g,
      (__attribute__((address_space(3))) void*)lds, 16, 0, 0);
}

// ---------------- fp32 -> bf16 weight converts (one fused launch) ----------------
__global__ void cvt4_f32_to_bf16(const float* __restrict__ s0, const float* __restrict__ s1,
                                 const float* __restrict__ s2, const float* __restrict__ s3,
                                 __bf16* __restrict__ d0, __bf16* __restrict__ d1,
                                 __bf16* __restrict__ d2, __bf16* __restrict__ d3, int n4each) {
  int i = blockIdx.x * blockDim.x + threadIdx.x;
  int which = i / n4each, j = i - which * n4each;
  const float* s = which == 0 ? s0 : which == 1 ? s1 : which == 2 ? s2 : s3;
  __bf16* d = which == 0 ? d0 : which == 1 ? d1 : which == 2 ? d2 : d3;
  float4 f = ((const float4*)s)[j];
  union { __bf16 h[4]; uint2 u; } p;
  p.h[0] = (__bf16)f.x; p.h[1] = (__bf16)f.y;
  p.h[2] = (__bf16)f.z; p.h[3] = (__bf16)f.w;
  ((uint2*)d)[j] = p.u;
}

// ---------------- fused QKV GEMM (R10/R11-proven) ----------------
__global__ __launch_bounds__(256, 2)
void gemm_qkv(const float* __restrict__ qin, const float* __restrict__ kin,
              const float* __restrict__ vin, const __bf16* __restrict__ Wcat,
              const float* __restrict__ bq, const float* __restrict__ bk,
              const float* __restrict__ bv,
              __bf16* __restrict__ Qh, __bf16* __restrict__ Kh,
              __bf16* __restrict__ Vt, float qscale)
{
  __shared__ __align__(16) __bf16 As[128 * 32];
  __shared__ __align__(16) __bf16 Bs[128 * 32];
  const int tid = threadIdx.x;
  const int wave = tid >> 6, lane = tid & 63;
  const int wr = wave >> 1, wc = wave & 1;
  const int r = lane & 15, hi = lane >> 4;
  const int lin = (int)blockIdx.y * 24 + (int)blockIdx.x;   // 0..1535
  const int xcd = lin & 7, s8 = lin >> 3;                   // s8: 0..191
  const int my = (xcd << 3) | (s8 / 24);                    // 0..63
  const int mx = s8 % 24;                                   // 0..23
  const int m0 = my * 128, n0 = mx * 128;
  const int proj = n0 >> 10;                       // block-uniform: 0=Q 1=K 2=V
  const float* Xa = proj == 0 ? qin : proj == 1 ? kin : vin;

  f32x4 acc[4][4] = {};

  for (int k0 = 0; k0 < Kdim; k0 += 32) {
    #pragma unroll
    for (int c = 0; c < 2; ++c) {
      int chunk = c * 256 + tid;
      int row = chunk >> 2;
      int cw = chunk & 3;
      int hc = cw ^ (row & 3);
      const float* src = Xa + (size_t)(m0 + row) * Kdim + k0 + hc * 8;
      float4 f0 = *(const float4*)src;
      float4 f1 = *(const float4*)(src + 4);
      union { __bf16 h[8]; uint4 u; } pk;
      pk.h[0] = (__bf16)f0.x; pk.h[1] = (__bf16)f0.y;
      pk.h[2] = (__bf16)f0.z; pk.h[3] = (__bf16)f0.w;
      pk.h[4] = (__bf16)f1.x; pk.h[5] = (__bf16)f1.y;
      pk.h[6] = (__bf16)f1.z; pk.h[7] = (__bf16)f1.w;
      *(uint4*)&As[(size_t)chunk * 8] = pk.u;
    }
    #pragma unroll
    for (int c = 0; c < 2; ++c) {
      int chunk = c * 256 + wave * 64 + lane;
      int row = chunk >> 2;
      int hc = (chunk & 3) ^ (row & 3);
      gload_lds16(Wcat + (size_t)(n0 + row) * Kdim + k0 + hc * 8,
                  &Bs[(size_t)(c * 256 + wave * 64) * 8]);
    }
    __syncthreads();
    bf16x8 af[4], bfr[4];
    #pragma unroll
    for (int m = 0; m < 4; ++m) {
      int rowl = wr * 64 + m * 16 + r;
      af[m] = *(const bf16x8*)&As[rowl * 32 + ((hi ^ (rowl & 3)) * 8)];
    }
    #pragma unroll
    for (int n = 0; n < 4; ++n) {
      int rowl = wc * 64 + n * 16 + r;
      bfr[n] = *(const bf16x8*)&Bs[rowl * 32 + ((hi ^ (rowl & 3)) * 8)];
    }
    #pragma unroll
    for (int m = 0; m < 4; ++m)
      #pragma unroll
      for (int n = 0; n < 4; ++n)
        acc[m][n] = __builtin_amdgcn_mfma_f32_16x16x32_bf16(af[m], bfr[n], acc[m][n], 0, 0, 0);
    __syncthreads();
  }

  const float* bias = proj == 0 ? bq : proj == 1 ? bk : bv;
  if (proj < 2) {
    __bf16* out = proj == 0 ? Qh : Kh;
    const float sc = proj == 0 ? qscale : 1.0f;
    #pragma unroll
    for (int m = 0; m < 4; ++m)
      #pragma unroll
      for (int n = 0; n < 4; ++n)
        #pragma unroll
        for (int rg = 0; rg < 4; ++rg) {
          int row_g = m0 + wr * 64 + m * 16 + hi * 4 + rg;
          int col_g = n0 + wc * 64 + n * 16 + r;
          int c = col_g & 1023, h = c >> 6, d = c & 63;
          int b = row_g >> 11, s = row_g & (Sc - 1);
          float v = (acc[m][n][rg] + bias[c]) * sc;
          out[((((size_t)b * Hc + h) * Sc + s) << 6) + d] = (__bf16)v;
        }
  } else {
    #pragma unroll
    for (int m = 0; m < 4; ++m)
      #pragma unroll
      for (int n = 0; n < 4; ++n) {
        int row0 = m0 + wr * 64 + m * 16 + hi * 4;
        int col_g = n0 + wc * 64 + n * 16 + r;
        int c = col_g & 1023, h = c >> 6, d = c & 63;
        int b = row0 >> 11, s = row0 & (Sc - 1);
        union { __bf16 hh[4]; uint2 u; } w;
        #pragma unroll
        for (int rg = 0; rg < 4; ++rg)
          w.hh[rg] = (__bf16)(acc[m][n][rg] + bias[c]);
        *(uint2*)&Vt[((((size_t)b * Hc + h) * HDc + d) << 11) + s] = w.u;
      }
  }
}

// ---------------- out-projection GEMM (R10/R11-proven) ----------------
__global__ __launch_bounds__(256, 2)
void gemm_out(const __bf16* __restrict__ A, const __bf16* __restrict__ Bw,
              const float* __restrict__ bias, float* __restrict__ outp)
{
  __shared__ __align__(16) __bf16 As[128 * 32];
  __shared__ __align__(16) __bf16 Bs[128 * 32];
  const int tid = threadIdx.x;
  const int wave = tid >> 6, lane = tid & 63;
  const int wr = wave >> 1, wc = wave & 1;
  const int r = lane & 15, hi = lane >> 4;
  const int lin = (int)blockIdx.y * 8 + (int)blockIdx.x;    // 0..511
  const int xcd = lin & 7, s8 = lin >> 3;                   // 0..63
  const int m0 = (((xcd << 3) | (s8 >> 3)) ) * 128;
  const int n0 = (s8 & 7) * 128;

  f32x4 acc[4][4] = {};

  for (int k0 = 0; k0 < Kdim; k0 += 32) {
    #pragma unroll
    for (int c = 0; c < 2; ++c) {
      int chunk = c * 256 + wave * 64 + lane;
      int row = chunk >> 2;
      int hc = (chunk & 3) ^ (row & 3);
      gload_lds16(A  + (size_t)(m0 + row) * Kdim + k0 + hc * 8,
                  &As[(size_t)(c * 256 + wave * 64) * 8]);
      gload_lds16(Bw + (size_t)(n0 + row) * Kdim + k0 + hc * 8,
                  &Bs[(size_t)(c * 256 + wave * 64) * 8]);
    }
    __syncthreads();
    bf16x8 af[4], bfr[4];
    #pragma unroll
    for (int m = 0; m < 4; ++m) {
      int rowl = wr * 64 + m * 16 + r;
      af[m] = *(const bf16x8*)&As[rowl * 32 + ((hi ^ (rowl & 3)) * 8)];
    }
    #pragma unroll
    for (int n = 0; n < 4; ++n) {
      int rowl = wc * 64 + n * 16 + r;
      bfr[n] = *(const bf16x8*)&Bs[rowl * 32 + ((hi ^ (rowl & 3)) * 8)];
    }
    #pragma unroll
    for (int m = 0; m < 4; ++m)
      #pragma unroll
      for (int n = 0; n < 4; ++n)
        acc[m][n] = __builtin_amdgcn_mfma_f32_16x16x32_bf16(af[m], bfr[n], acc[m][n], 0, 0, 0);
    __syncthreads();
  }

  #pragma unroll
  for (int m = 0; m < 4; ++m)
    #pragma unroll
    for (int n = 0; n < 4; ++n)
      #pragma unroll
      for (int rg = 0; rg < 4; ++rg) {
        int row_g = m0 + wr * 64 + m * 16 + hi * 4 + rg;
        int col_g = n0 + wc * 64 + n * 16 + r;
        outp[(size_t)row_g * Dc + col_g] = acc[m][n][rg] + bias[col_g];
      }
}

// ---------------- causal flash attention: 32x32 MFMA, lane-local softmax ----
// Wave owns 32 q-rows (qh = 0..63), full causal KV range in 32-kv tiles.
// Swapped QK^T via mfma_32x32x16: C col = q = lane&31, row = kv =
// (reg&3)+8*(reg>>2)+4*(lane>>5). Each lane: ONE q-column, 16/32 kv in-reg.
//  -> max/sum: 15 in-lane ops + one shfl_xor(32). m,l are SCALARS per lane.
//  -> P->B-operand: 8 cvt_pk + 4 permlane32_swap (distinct operands), 0 shfl.
// Qh/Kh: [B*H][S][64] bf16 (Q pre-scaled by log2e/8). Vt: [B*H][64][S].
__global__ __launch_bounds__(128, 2)
void attn_causal(const __bf16* __restrict__ Qh, const __bf16* __restrict__ Kh,
                 const __bf16* __restrict__ Vt, __bf16* __restrict__ outp)
{
  const int tid = threadIdx.x;
  const int wave = tid >> 6, lane = tid & 63;
  const int c32 = lane & 31;          // q-column / A-row index
  const int h5 = lane >> 5;           // half-wave
  // XCD swizzle (R10-proven): all 32 blocks of one bh on one XCD.
  const int lin = (int)blockIdx.y * 32 + (int)blockIdx.x;   // 0..2047
  const int xcd = lin & 7, s8 = lin >> 3;                   // s8: 0..255
  const int bh = (xcd << 3) | (s8 >> 5);                    // 0..63
  const int px = s8 & 31;                                   // 0..31
  const int qh = wave ? (63 - px) : px;                     // paired balance
  const int q0 = qh * 32;
  const __bf16* Q = Qh + (size_t)bh * (Sc * HDc);
  const __bf16* K = Kh + (size_t)bh * (Sc * HDc);
  const __bf16* V = Vt + (size_t)bh * (HDc * Sc);

  // Q B-operand frags: lane supplies B[k=8*h5+j][col=c32], d = dc*16+8*h5+j
  bf16x8 qf[4];
  #pragma unroll
  for (int dc = 0; dc < 4; ++dc)
    qf[dc] = *(const bf16x8*)&Q[(size_t)(q0 + c32) * 64 + dc * 16 + h5 * 8];

  f32x16 o0 = {}, o1 = {};    // O^T: col q=c32, row d=(reg&3)+8(reg>>2)+4h5 (+32)
  float mrow = -1e30f, lrow = 0.f;

  const int T = qh + 1;       // 32-kv tiles
  bf16x8 kf[4], vf0[2], vf1[2];

  // preload tile 0
  #pragma unroll
  for (int dc = 0; dc < 4; ++dc)
    kf[dc] = *(const bf16x8*)&K[(size_t)c32 * 64 + dc * 16 + h5 * 8];
  #pragma unroll
  for (int kc = 0; kc < 2; ++kc) {
    vf0[kc] = *(const bf16x8*)&V[(size_t)c32 * Sc + kc * 16 + h5 * 8];
    vf1[kc] = *(const bf16x8*)&V[(size_t)(32 + c32) * Sc + kc * 16 + h5 * 8];
  }

  for (int t = 0; t < T; ++t) {
    const bool diag = (t == T - 1);
    const int kvn = (t + 1) * 32;

    // ---- QK^T: S^T[kv][q] over one 32x32 tile, K=64 via 4 chained MFMAs ----
    f32x16 sn = {};
    __builtin_amdgcn_s_setprio(1);
    sn = __builtin_amdgcn_mfma_f32_32x32x16_bf16(kf[0], qf[0], sn, 0, 0, 0);
    sn = __builtin_amdgcn_mfma_f32_32x32x16_bf16(kf[1], qf[1], sn, 0, 0, 0);
    sn = __builtin_amdgcn_mfma_f32_32x32x16_bf16(kf[2], qf[2], sn, 0, 0, 0);
    sn = __builtin_amdgcn_mfma_f32_32x32x16_bf16(kf[3], qf[3], sn, 0, 0, 0);
    __builtin_amdgcn_s_setprio(0);

    if (diag) {
      #pragma unroll
      for (int reg = 0; reg < 16; ++reg)
        if ((reg & 3) + 8 * (reg >> 2) + 4 * h5 > c32) sn[reg] = -1e30f;
    }

    // row-max: 15 in-lane + cross-half via proven shfl_xor(32)
    float mx = fmaxf(fmaxf(fmaxf(sn[0], sn[1]), fmaxf(sn[2], sn[3])),
                     fmaxf(fmaxf(sn[4], sn[5]), fmaxf(sn[6], sn[7])));
    mx = fmaxf(mx, fmaxf(fmaxf(fmaxf(sn[8], sn[9]), fmaxf(sn[10], sn[11])),
                         fmaxf(fmaxf(sn[12], sn[13]), fmaxf(sn[14], sn[15]))));
    mx = fmaxf(mx, __shfl_xor(mx, 32));
    if (__any(mx > mrow + 8.f)) {        // T13 defer-max (log2 domain)
      float mnew = fmaxf(mrow, mx);
      float sc = __builtin_exp2f(mrow - mnew);
      lrow *= sc;
      o0 *= sc;
      o1 *= sc;
      mrow = mnew;
    }
    float rs = 0.f;
    #pragma unroll
    for (int reg = 0; reg < 16; ++reg) {
      float p = __builtin_exp2f(sn[reg] - mrow);
      sn[reg] = p;
      rs += p;
    }
    rs += __shfl_xor(rs, 32);
    lrow += rs;

    // pack P -> B-operand: 8 cvt_pk + 4 permlane32_swap (distinct operands)
    uint32_t u0, u1, u2, u3, u4, u5, u6, u7;
    asm("v_cvt_pk_bf16_f32 %0, %1, %2" : "=v"(u0) : "v"(sn[0]),  "v"(sn[1]));
    asm("v_cvt_pk_bf16_f32 %0, %1, %2" : "=v"(u1) : "v"(sn[2]),  "v"(sn[3]));
    asm("v_cvt_pk_bf16_f32 %0, %1, %2" : "=v"(u2) : "v"(sn[4]),  "v"(sn[5]));
    asm("v_cvt_pk_bf16_f32 %0, %1, %2" : "=v"(u3) : "v"(sn[6]),  "v"(sn[7]));
    asm("v_cvt_pk_bf16_f32 %0, %1, %2" : "=v"(u4) : "v"(sn[8]),  "v"(sn[9]));
    asm("v_cvt_pk_bf16_f32 %0, %1, %2" : "=v"(u5) : "v"(sn[10]), "v"(sn[11]));
    asm("v_cvt_pk_bf16_f32 %0, %1, %2" : "=v"(u6) : "v"(sn[12]), "v"(sn[13]));
    asm("v_cvt_pk_bf16_f32 %0, %1, %2" : "=v"(u7) : "v"(sn[14]), "v"(sn[15]));
    asm("v_permlane32_swap_b32 %0, %1" : "+v"(u0), "+v"(u2));
    asm("v_permlane32_swap_b32 %0, %1" : "+v"(u1), "+v"(u3));
    asm("v_permlane32_swap_b32 %0, %1" : "+v"(u4), "+v"(u6));
    asm("v_permlane32_swap_b32 %0, %1" : "+v"(u5), "+v"(u7));
    union { uint32_t w[4]; bf16x8 v; } pb0, pb1;
    pb0.w[0] = u0; pb0.w[1] = u1; pb0.w[2] = u2; pb0.w[3] = u3;  // kv 0..15
    pb1.w[0] = u4; pb1.w[1] = u5; pb1.w[2] = u6; pb1.w[3] = u7;  // kv 16..31

    // prefetch next K tile (kf dead after QK)
    if (t + 1 < T) {
      #pragma unroll
      for (int dc = 0; dc < 4; ++dc)
        kf[dc] = *(const bf16x8*)&K[(size_t)(kvn + c32) * 64 + dc * 16 + h5 * 8];
    }

    // ---- PV: O^T += V^T-frag * P-frag ----
    __builtin_amdgcn_s_setprio(1);
    o0 = __builtin_amdgcn_mfma_f32_32x32x16_bf16(vf0[0], pb0.v, o0, 0, 0, 0);
    o0 = __builtin_amdgcn_mfma_f32_32x32x16_bf16(vf0[1], pb1.v, o0, 0, 0, 0);
    o1 = __builtin_amdgcn_mfma_f32_32x32x16_bf16(vf1[0], pb0.v, o1, 0, 0, 0);
    o1 = __builtin_amdgcn_mfma_f32_32x32x16_bf16(vf1[1], pb1.v, o1, 0, 0, 0);
    __builtin_amdgcn_s_setprio(0);

    // prefetch next V tile (vf dead after PV)
    if (t + 1 < T) {
      #pragma unroll
      for (int kc = 0; kc < 2; ++kc) {
        vf0[kc] = *(const bf16x8*)&V[(size_t)c32 * Sc + kvn + kc * 16 + h5 * 8];
        vf1[kc] = *(const bf16x8*)&V[(size_t)(32 + c32) * Sc + kvn + kc * 16 + h5 * 8];
      }
    }
  }

  // ---- epilogue: all of a lane's outputs share q-col c32 -> one scalar inv ----
  const int b = bh >> 4, h = bh & 15;
  const float inv = 1.f / lrow;
  __bf16* obase = outp + ((size_t)b * Sc + q0 + c32) * Dc + h * 64;
  #pragma unroll
  for (int rq = 0; rq < 4; ++rq) {               // d = rr + 8*rq + 4*h5
    union { __bf16 hh[4]; uint2 u; } w;
    #pragma unroll
    for (int rr = 0; rr < 4; ++rr) w.hh[rr] = (__bf16)(o0[rq * 4 + rr] * inv);
    *(uint2*)&obase[rq * 8 + h5 * 4] = w.u;
  }
  #pragma unroll
  for (int rq = 0; rq < 4; ++rq) {               // d = 32 + rr + 8*rq + 4*h5
    union { __bf16 hh[4]; uint2 u; } w;
    #pragma unroll
    for (int rr = 0; rr < 4; ++rr) w.hh[rr] = (__bf16)(o1[rq * 4 + rr] * inv);
    *(uint2*)&obase[32 + rq * 8 + h5 * 4] = w.u;
  }
}

// ---------------- launch ----------------
extern "C" void kernel_launch(void* const* d_in, const int* in_sizes, int n_in,
                              void* d_out, int out_size, void* d_ws, size_t ws_size,
                              hipStream_t stream) {
  const float* q  = (const float*)d_in[0];
  const float* k  = (const float*)d_in[1];
  const float* v  = (const float*)d_in[2];
  const float* Wq = (const float*)d_in[4];
  const float* bq = (const float*)d_in[5];
  const float* Wk = (const float*)d_in[6];
  const float* bk = (const float*)d_in[7];
  const float* Wv = (const float*)d_in[8];
  const float* bv = (const float*)d_in[9];
  const float* Wo = (const float*)d_in[10];
  const float* bo = (const float*)d_in[11];

  char* ws = (char*)d_ws;
  constexpr size_t MB = 1u << 20;
  __bf16* Wcat = (__bf16*)(ws + 0 * MB);   // Wq|Wk|Wv rows, 6 MB
  __bf16* Wkb  = (__bf16*)(ws + 2 * MB);
  __bf16* Wvb  = (__bf16*)(ws + 4 * MB);
  __bf16* Wob  = (__bf16*)(ws + 6 * MB);
  __bf16* Xbf  = (__bf16*)(ws + 8 * MB);   // attn out, 16 MB
  __bf16* QhB  = (__bf16*)(ws + 24 * MB);
  __bf16* KhB  = (__bf16*)(ws + 40 * MB);
  __bf16* VtB  = (__bf16*)(ws + 56 * MB);  // V^T: [B*H][64][S]

  const int nW4 = (Dc * Dc) / 4;           // 262144
  cvt4_f32_to_bf16<<<(4 * nW4) / 256, 256, 0, stream>>>(Wq, Wk, Wv, Wo, Wcat, Wkb, Wvb, Wob, nW4);

  const float qscale = 0.125f * 1.44269504f;  // fold 1/sqrt(64) and log2(e)
  gemm_qkv<<<dim3(24, Mrows / 128), 256, 0, stream>>>(q, k, v, Wcat, bq, bk, bv,
                                                      QhB, KhB, VtB, qscale);

  attn_causal<<<dim3(32, Bc * Hc), 128, 0, stream>>>(QhB, KhB, VtB, Xbf);

  gemm_out<<<dim3(8, Mrows / 128), 256, 0, stream>>>(Xbf, Wob, bo, (float*)d_out);
}